// Round 14
// baseline (3934.433 us; speedup 1.0000x reference)
//
#include <hip/hip_runtime.h>
#include <hip/hip_bf16.h>
#include <math.h>

#define NTOT   32768
#define NPER   4096
#define NGRAPH 8
#define EDGES  262144
#define HCH    128
#define EPSBN  1e-5f
#define BANKS  16
#define NBLK   512

typedef short bf16x8 __attribute__((ext_vector_type(8)));
typedef float f32x4  __attribute__((ext_vector_type(4)));

__device__ __forceinline__ float eluf(float x){ return x > 0.f ? x : expm1f(x); }
__device__ __forceinline__ ushort f2bf(float f){
    uint u = __float_as_uint(f);
    u += 0x7fffu + ((u >> 16) & 1u);          // round-to-nearest-even
    return (ushort)(u >> 16);
}
__device__ __forceinline__ float bf2f(ushort h){ return __uint_as_float(((uint)h) << 16); }
__device__ __forceinline__ float bfhi(uint p){ return __uint_as_float(p & 0xffff0000u); }
__device__ __forceinline__ float bflo(uint p){ return __uint_as_float(p << 16); }

// hand-rolled grid barrier: one single-use counter per sync point (zeroed each launch)
__device__ __forceinline__ void gbar(int* bar, int idx){
    __syncthreads();
    if (threadIdx.x == 0){
        __threadfence();
        __hip_atomic_fetch_add(&bar[idx], 1, __ATOMIC_ACQ_REL, __HIP_MEMORY_SCOPE_AGENT);
        while (__hip_atomic_load(&bar[idx], __ATOMIC_ACQUIRE, __HIP_MEMORY_SCOPE_AGENT) < NBLK)
            __builtin_amdgcn_s_sleep(2);
        __threadfence();
    }
    __syncthreads();
}

// ---------------- CSR build ----------------
__global__ __launch_bounds__(256) void k_hist(const int* __restrict__ dst, int* __restrict__ deg){
    int e = blockIdx.x * 256 + threadIdx.x;
    atomicAdd(&deg[dst[e]], 1);
}

__global__ __launch_bounds__(1024) void k_scan(const int* __restrict__ deg, int* __restrict__ rowptr,
                                               int* __restrict__ cursor){
    __shared__ int part[1024];
    int t = threadIdx.x;
    const int chunk = NTOT / 1024;
    int base = t * chunk;
    int s = 0;
    for (int j = 0; j < chunk; ++j) s += deg[base + j];
    part[t] = s; __syncthreads();
    for (int off = 1; off < 1024; off <<= 1){
        int v = (t >= off) ? part[t - off] : 0;
        __syncthreads();
        part[t] += v;
        __syncthreads();
    }
    int run = part[t] - s;
    for (int j = 0; j < chunk; ++j){
        rowptr[base + j] = run; cursor[base + j] = run;
        run += deg[base + j];
    }
    if (t == 1023) rowptr[NTOT] = run;
}

__global__ __launch_bounds__(256) void k_scatter(const int* __restrict__ src, const int* __restrict__ dst,
                                                 const float* __restrict__ L, int* __restrict__ cursor,
                                                 int2* __restrict__ epk){
    int e = blockIdx.x * 256 + threadIdx.x;
    int d = dst[e];
    int pos = atomicAdd(&cursor[d], 1);
    int2 pv; pv.x = src[e]; pv.y = __float_as_int(L[e]);
    epk[pos] = pv;
}

// ---------------- per-graph mask count ----------------
__global__ __launch_bounds__(256) void k_cnt(const float* __restrict__ mask, float* __restrict__ gcnt){
    __shared__ float red[4];
    int g = blockIdx.x, t = threadIdx.x;
    float s = 0.f;
    for (int i = t; i < NPER; i += 256) s += mask[g * NPER + i];
    #pragma unroll
    for (int off = 32; off > 0; off >>= 1) s += __shfl_down(s, off);
    if ((t & 63) == 0) red[t >> 6] = s;
    __syncthreads();
    if (t == 0) gcnt[g] = red[0] + red[1] + red[2] + red[3];
}

// ---------------- one-time: all 30 layers' raw W -> fragment-native bf16 ----------------
__global__ __launch_bounds__(256) void k_wall(const float* __restrict__ Wb, uint4* __restrict__ Braw){
    int layer = blockIdx.x >> 4;
    int it = ((blockIdx.x & 15) << 8) | threadIdx.x;   // 0..4095
    int nt = it >> 9;
    int rem = it & 511;
    int kc = rem >> 6, l = rem & 63;
    int col = nt * 16 + (l & 15);
    int k0  = kc * 32 + (l >> 4) * 8;
    const float* W = Wb + (size_t)layer * 256 * HCH;
    ushort hi[8];
    #pragma unroll
    for (int q = 0; q < 8; ++q) hi[q] = f2bf(W[(size_t)(k0 + q) * HCH + col]);
    uint4 vh;
    vh.x = hi[0] | ((uint)hi[1] << 16); vh.y = hi[2] | ((uint)hi[3] << 16);
    vh.z = hi[4] | ((uint)hi[5] << 16); vh.w = hi[6] | ((uint)hi[7] << 16);
    Braw[(size_t)layer * 4096 + (size_t)(nt * 8 + kc) * 64 + l] = vh;
}

// ---------------- mega kernel: conv1 + 30 layers + final, manual grid barriers ----------------
__global__ __launch_bounds__(256, 2) void k_mega(
        const float* __restrict__ x, const float* __restrict__ mask,
        const float* __restrict__ W1, const float* __restrict__ b1,
        const float* __restrict__ bb, const float* __restrict__ gb,
        const float* __restrict__ betab, const float* __restrict__ g2,
        const float* __restrict__ beta2, const float* __restrict__ W2,
        const float* __restrict__ b2,
        const int* __restrict__ rowptr, const int2* __restrict__ epk,
        const float* __restrict__ gcnt, const uint4* __restrict__ Braw,
        float* H0, ushort* Uh0, ushort* Uh1,
        float* sums, float* gsum, float* out, int* bar)
{
    __shared__ ushort agg_lds[64 * 128];          // 16 KB raw bf16 agg, 16B-slot XOR swizzle
    __shared__ ushort a_sm[4][2][512];            // 8 KB per-wave u-half dbuf
    __shared__ float s_s[256], s_sh[256];
    __shared__ uint  s_avgpk[64];
    __shared__ float red[2][2][128];
    __shared__ float gred[2][128];
    __shared__ float sred[4][2][128];
    __shared__ float wred[4];

    const int t = threadIdx.x;
    const int w = t >> 6, lane = t & 63;
    const int rlo = lane & 15, kg = lane >> 4;
    const int bid = blockIdx.x;
    const int sb  = ((bid & 7) << 6) | (bid >> 3);   // graph -> XCD
    const int row0 = sb * 64;
    const int g0 = row0 >> 12;
    const int bank = bid & (BANKS - 1);
    int bidx = 0;

    auto acc8 = [](float* a, uint4 p, float wv){
        a[0] = fmaf(bflo(p.x), wv, a[0]); a[1] = fmaf(bfhi(p.x), wv, a[1]);
        a[2] = fmaf(bflo(p.y), wv, a[2]); a[3] = fmaf(bfhi(p.y), wv, a[3]);
        a[4] = fmaf(bflo(p.z), wv, a[4]); a[5] = fmaf(bfhi(p.z), wv, a[5]);
        a[6] = fmaf(bflo(p.w), wv, a[6]); a[7] = fmaf(bfhi(p.w), wv, a[7]);
    };

    // ================= phase: conv1 =================
    {
        int ch = t & 127, pr = t >> 7;
        float w0 = W1[ch], w1 = W1[128 + ch], w2 = W1[256 + ch], bv = b1[ch];
        float ls = 0.f, lss = 0.f;
        for (int it = 0; it < 32; ++it){
            int row = row0 + 2 * it + pr;
            const float* xr = x + (size_t)row * 3;
            float h = fmaf(xr[2], w2, fmaf(xr[1], w1, fmaf(xr[0], w0, bv)));
            H0[(size_t)row * HCH + ch] = h;
            float u = eluf(h);
            Uh0[(size_t)row * HCH + ch] = f2bf(u);
            ls += u; lss += u * u;
        }
        red[0][pr][ch] = ls; red[1][pr][ch] = lss;
        __syncthreads();
        if (t < 128){
            float* sb_ = sums + (size_t)bank * 512;
            atomicAdd(&sb_[t],       red[0][0][t] + red[0][1][t]);
            atomicAdd(&sb_[256 + t], red[1][0][t] + red[1][1][t]);
        }
    }
    gbar(bar, bidx++);

    const ushort* Ucur = Uh0; ushort* Unext = Uh1;
    for (int k = 0; k < 30; ++k){
        const int MODE = (k >> 1) & 1;
        const int RES  = k & 1;
        float* sums_k = sums + (size_t)k * BANKS * 512;
        float* sums_n = sums + (size_t)(k + 1) * BANKS * 512;
        const float* gsum_k = gsum + (size_t)k * NGRAPH * HCH;
        const bool nextg = (k < 29) && ((((k + 1) >> 1) & 1) == 1);
        float* gsum_next = nextg ? (gsum + (size_t)(k + 1) * NGRAPH * HCH) : nullptr;
        const uint4* Wfrag = Braw + (size_t)k * 4096;
        const float* bias  = bb + (size_t)k * HCH;
        const float* gamma = gb + (size_t)k * 256;
        const float* beta  = betab + (size_t)k * 256;

        // ================= phase: spmm (even outer layers) =================
        if (MODE == 0){
            const int rg = t >> 4;
            const int cl = t & 15;
            const int c8 = cl << 3;
            float sA[8] = {0,0,0,0,0,0,0,0}, qA[8] = {0,0,0,0,0,0,0,0};
            for (int q2 = 0; q2 < 4; ++q2){
                const int lrow = rg + q2 * 16;
                const int node = row0 + lrow;
                const int e0 = rowptr[node], e1 = rowptr[node + 1];
                float a[8] = {0,0,0,0,0,0,0,0};
                int e = e0;
                for (; e + 8 <= e1; e += 8){
                    int2 PV[8];
                    #pragma unroll
                    for (int q = 0; q < 8; ++q) PV[q] = epk[e + q];
                    uint4 P[8];
                    #pragma unroll
                    for (int q = 0; q < 8; ++q)
                        P[q] = *(const uint4*)(Ucur + (size_t)PV[q].x * HCH + c8);
                    #pragma unroll
                    for (int q = 0; q < 8; ++q) acc8(a, P[q], __int_as_float(PV[q].y));
                }
                for (; e + 2 <= e1; e += 2){
                    int2 pv0 = epk[e], pv1 = epk[e + 1];
                    uint4 p0 = *(const uint4*)(Ucur + (size_t)pv0.x * HCH + c8);
                    uint4 p1 = *(const uint4*)(Ucur + (size_t)pv1.x * HCH + c8);
                    acc8(a, p0, __int_as_float(pv0.y));
                    acc8(a, p1, __int_as_float(pv1.y));
                }
                if (e < e1){
                    int2 pv = epk[e];
                    uint4 p = *(const uint4*)(Ucur + (size_t)pv.x * HCH + c8);
                    acc8(a, p, __int_as_float(pv.y));
                }
                uint4 o;
                o.x = (uint)f2bf(a[0]) | ((uint)f2bf(a[1]) << 16);
                o.y = (uint)f2bf(a[2]) | ((uint)f2bf(a[3]) << 16);
                o.z = (uint)f2bf(a[4]) | ((uint)f2bf(a[5]) << 16);
                o.w = (uint)f2bf(a[6]) | ((uint)f2bf(a[7]) << 16);
                int pslot = cl ^ (lrow & 7);
                *(uint4*)&agg_lds[lrow * 128 + pslot * 8] = o;
                #pragma unroll
                for (int j = 0; j < 8; ++j){ sA[j] += a[j]; qA[j] += a[j] * a[j]; }
            }
            #pragma unroll
            for (int j = 0; j < 8; ++j){
                sA[j] += __shfl_xor(sA[j], 16); sA[j] += __shfl_xor(sA[j], 32);
                qA[j] += __shfl_xor(qA[j], 16); qA[j] += __shfl_xor(qA[j], 32);
            }
            if ((lane >> 4) == 0){
                #pragma unroll
                for (int j = 0; j < 8; ++j){ sred[w][0][c8 + j] = sA[j]; sred[w][1][c8 + j] = qA[j]; }
            }
            __syncthreads();
            if (t < 128){
                float s = 0.f, q = 0.f;
                #pragma unroll
                for (int q2 = 0; q2 < 4; ++q2){ s += sred[q2][0][t]; q += sred[q2][1][t]; }
                float* sb_ = sums_k + (size_t)bank * 512;
                atomicAdd(&sb_[128 + t], s);
                atomicAdd(&sb_[384 + t], q);
            }
            gbar(bar, bidx++);
        }

        // ================= phase: gemm =================
        {
            float m, ex2;
            if (MODE == 1 && t >= 128){
                float S1 = 0.f, S2 = 0.f;
                #pragma unroll
                for (int g = 0; g < NGRAPH; ++g){
                    float a = gsum_k[g * 128 + (t - 128)] / gcnt[g];
                    S1 += a; S2 += a * a;
                }
                m = S1 * (1.f / NGRAPH); ex2 = S2 * (1.f / NGRAPH);
            } else {
                float S = 0.f, Q = 0.f;
                #pragma unroll
                for (int b = 0; b < BANKS; ++b){
                    S += sums_k[(size_t)b * 512 + t];
                    Q += sums_k[(size_t)b * 512 + 256 + t];
                }
                m = S * (1.f / NTOT); ex2 = Q * (1.f / NTOT);
            }
            float var = ex2 - m * m;
            float sc = gamma[t] * rsqrtf(var + EPSBN);
            s_s[t] = sc; s_sh[t] = beta[t] - m * sc;
        }
        __syncthreads();
        if (MODE == 1){
            if (t < 64){
                float a0 = gsum_k[g0 * 128 + 2 * t]     / gcnt[g0];
                float a1 = gsum_k[g0 * 128 + 2 * t + 1] / gcnt[g0];
                float z0 = fmaf(a0, s_s[128 + 2 * t],     s_sh[128 + 2 * t]);
                float z1 = fmaf(a1, s_s[128 + 2 * t + 1], s_sh[128 + 2 * t + 1]);
                s_avgpk[t] = (uint)f2bf(z0) | ((uint)f2bf(z1) << 16);
            }
            __syncthreads();
        }

        for (int tile = 0; tile < 2; ++tile){
            const int wr0g = row0 + tile * 32 + (w & 1) * 16;    // global row base of this wave
            const int lbase = tile * 32 + (w & 1) * 16;          // local agg row base
            const int colbase = (w >> 1) * 64;
            const int ntb = (w >> 1) * 4;

            auto stageU = [&](int kc, ushort* dst){
                int row = lane >> 2, sl4 = lane & 3;
                int chb = kc * 32 + sl4 * 8;
                const ushort* sp = Ucur + (size_t)(wr0g + row) * HCH + chb;
                uint4 v = *(const uint4*)sp;
                uint in4[4] = {v.x, v.y, v.z, v.w};
                uint o[4];
                #pragma unroll
                for (int j = 0; j < 4; ++j){
                    int c = chb + 2 * j;
                    float z0 = fmaf(bflo(in4[j]), s_s[c],     s_sh[c]);
                    float z1 = fmaf(bfhi(in4[j]), s_s[c + 1], s_sh[c + 1]);
                    o[j] = (uint)f2bf(z0) | ((uint)f2bf(z1) << 16);
                }
                int slot = sl4 ^ ((row >> 1) & 3);
                uint4 wv = {o[0], o[1], o[2], o[3]};
                *(uint4*)&dst[row * 32 + slot * 8] = wv;
            };

            f32x4 acc[4];
            #pragma unroll
            for (int n = 0; n < 4; ++n) acc[n] = (f32x4){0.f, 0.f, 0.f, 0.f};

            stageU(0, &a_sm[w][0][0]);
            for (int kc = 0; kc < 8; ++kc){
                union { uint u[4]; bf16x8 v; } ah;
                if (kc < 4){
                    ushort* cur = &a_sm[w][kc & 1][0];
                    int slot = kg ^ ((rlo >> 1) & 3);
                    uint4 c0 = *(const uint4*)&cur[rlo * 32 + slot * 8];
                    ah.u[0] = c0.x; ah.u[1] = c0.y; ah.u[2] = c0.z; ah.u[3] = c0.w;
                    if (kc + 1 < 4) stageU(kc + 1, &a_sm[w][(kc & 1) ^ 1][0]);
                } else if (MODE == 0){
                    int lrow = lbase + rlo;
                    int ps = (((kc - 4) << 2) | kg) ^ (lrow & 7);
                    uint4 c0 = *(const uint4*)&agg_lds[lrow * 128 + ps * 8];
                    int cb = 128 + (kc - 4) * 32 + kg * 8;
                    uint in4[4] = {c0.x, c0.y, c0.z, c0.w};
                    #pragma unroll
                    for (int j = 0; j < 4; ++j){
                        int c = cb + 2 * j;
                        float z0 = fmaf(bflo(in4[j]), s_s[c],     s_sh[c]);
                        float z1 = fmaf(bfhi(in4[j]), s_s[c + 1], s_sh[c + 1]);
                        ah.u[j] = (uint)f2bf(z0) | ((uint)f2bf(z1) << 16);
                    }
                } else {
                    int base2 = (kc - 4) * 16 + kg * 4;
                    ah.u[0] = s_avgpk[base2 + 0]; ah.u[1] = s_avgpk[base2 + 1];
                    ah.u[2] = s_avgpk[base2 + 2]; ah.u[3] = s_avgpk[base2 + 3];
                }
                #pragma unroll
                for (int n = 0; n < 4; ++n){
                    const int nt = ntb + n;
                    union { uint4 q; bf16x8 v; } bh;
                    bh.q = Wfrag[(size_t)(nt * 8 + kc) * 64 + lane];
                    acc[n] = __builtin_amdgcn_mfma_f32_16x16x32_bf16(ah.v, bh.v, acc[n], 0, 0, 0);
                }
            }

            // epilogue
            const int r0 = wr0g + kg * 4;
            float mk[4] = {0.f, 0.f, 0.f, 0.f};
            if (gsum_next){ mk[0] = mask[r0]; mk[1] = mask[r0+1]; mk[2] = mask[r0+2]; mk[3] = mask[r0+3]; }
            #pragma unroll
            for (int n = 0; n < 4; ++n){
                const int c = colbase + n * 16 + rlo;
                const float bc = bias[c];
                float s = 0.f, q = 0.f, g = 0.f;
                #pragma unroll
                for (int r = 0; r < 4; ++r){
                    int row = r0 + r;
                    float h = acc[n][r] + bc;
                    if (RES){
                        h += H0[(size_t)row * HCH + c];
                        H0[(size_t)row * HCH + c] = h;
                    }
                    float u = eluf(h);
                    Unext[(size_t)row * HCH + c] = f2bf(u);
                    s += u; q += u * u;
                    if (gsum_next) g = fmaf(u, mk[r], g);
                }
                s += __shfl_xor(s, 16); s += __shfl_xor(s, 32);
                q += __shfl_xor(q, 16); q += __shfl_xor(q, 32);
                if (gsum_next){ g += __shfl_xor(g, 16); g += __shfl_xor(g, 32); }
                if (kg == 0){
                    red[0][w & 1][c] = s;
                    red[1][w & 1][c] = q;
                    if (gsum_next) gred[w & 1][c] = g;
                }
            }
            __syncthreads();
            if (t < 128){
                float a = red[0][0][t] + red[0][1][t];
                float b = red[1][0][t] + red[1][1][t];
                float* sb_ = sums_n + (size_t)bank * 512;
                atomicAdd(&sb_[t], a);
                atomicAdd(&sb_[256 + t], b);
                if (gsum_next)
                    atomicAdd(&gsum_next[g0 * 128 + t], gred[0][t] + gred[1][t]);
            }
            __syncthreads();
        }
        gbar(bar, bidx++);
        const ushort* tmpc = Ucur; Ucur = Unext; Unext = (ushort*)tmpc;
    }

    // ================= phase: final =================
    {
        if (t < 128){
            const float* sums30 = sums + (size_t)30 * BANKS * 512;
            float S = 0.f, Q = 0.f;
            #pragma unroll
            for (int b = 0; b < BANKS; ++b){
                S += sums30[(size_t)b * 512 + t];
                Q += sums30[(size_t)b * 512 + 256 + t];
            }
            float m   = S * (1.f / NTOT);
            float ex2 = Q * (1.f / NTOT);
            float var = ex2 - m * m;
            float sc = g2[t] * rsqrtf(var + EPSBN);
            s_s[t] = sc; s_sh[t] = beta2[t] - m * sc;
        }
        __syncthreads();
        int ch = t & 127, pr = t >> 7;
        int wid = t >> 6;
        float w2 = W2[ch];
        float b2v = b2[0];
        for (int it = 0; it < 32; ++it){
            int rowa = row0 + it * 2;
            int row  = rowa + pr;
            float u = bf2f(Ucur[(size_t)row * HCH + ch]);
            float v = (u * s_s[ch] + s_sh[ch]) * w2;
            #pragma unroll
            for (int off = 32; off > 0; off >>= 1) v += __shfl_down(v, off);
            if (lane == 0) wred[wid] = v;
            __syncthreads();
            if (t == 0)   out[rowa]     = wred[0] + wred[1] + b2v + x[(size_t)rowa * 3];
            if (t == 128) out[rowa + 1] = wred[2] + wred[3] + b2v + x[(size_t)(rowa + 1) * 3];
            __syncthreads();
        }
    }
}

// ---------------- host ----------------
extern "C" void kernel_launch(void* const* d_in, const int* in_sizes, int n_in,
                              void* d_out, int out_size, void* d_ws, size_t ws_size,
                              hipStream_t stream){
    const float* x    = (const float*)d_in[0];
    const float* L    = (const float*)d_in[1];
    const float* mask = (const float*)d_in[2];
    const float* W1   = (const float*)d_in[3];
    const float* b1   = (const float*)d_in[4];
    const float* Wb   = (const float*)d_in[5];
    const float* bb   = (const float*)d_in[6];
    const float* gb   = (const float*)d_in[7];
    const float* betab= (const float*)d_in[8];
    const float* g2   = (const float*)d_in[9];
    const float* beta2= (const float*)d_in[10];
    const float* W2   = (const float*)d_in[11];
    const float* b2   = (const float*)d_in[12];
    const int*   src  = (const int*)d_in[13];
    const int*   dst  = (const int*)d_in[14];

    char* base = (char*)d_ws;
    size_t off = 0;
    auto alloc = [&](size_t bytes)->char*{
        char* r = base + off;
        off = (off + bytes + 255) & ~(size_t)255;
        return r;
    };
    float* sums  = (float*)alloc((size_t)31 * BANKS * 512 * sizeof(float));  // banked BN stats
    float* gsum  = (float*)alloc(30 * NGRAPH * HCH * sizeof(float));
    int*   deg   = (int*)  alloc(NTOT * sizeof(int));
    int*   bar   = (int*)  alloc(64 * sizeof(int));                // grid-barrier counters
    size_t zero_bytes = off;                                       // zeroed once per launch
    float* gcnt  = (float*)alloc(NGRAPH * sizeof(float));
    int*   cursor= (int*)  alloc(NTOT * sizeof(int));
    int*   rowptr= (int*)  alloc((NTOT + 1) * sizeof(int));
    int2*  epk   = (int2*) alloc(EDGES * sizeof(int2));
    float* H0    = (float*)alloc((size_t)NTOT * HCH * sizeof(float));
    ushort* Uh0  = (ushort*)alloc((size_t)NTOT * HCH * sizeof(ushort));
    ushort* Uh1  = (ushort*)alloc((size_t)NTOT * HCH * sizeof(ushort));
    uint4* Braw  = (uint4*)alloc((size_t)30 * 4096 * sizeof(uint4));   // 1.97 MB raw-W fragments
    float* outp  = (float*)d_out;
    (void)ws_size; (void)in_sizes; (void)n_in; (void)out_size; (void)deg; (void)L;

    hipMemsetAsync(d_ws, 0, zero_bytes, stream);
    k_wall   <<<480, 256, 0, stream>>>(Wb, Braw);
    k_hist   <<<EDGES / 256, 256, 0, stream>>>(dst, deg);
    k_scan   <<<1, 1024, 0, stream>>>(deg, rowptr, cursor);
    k_scatter<<<EDGES / 256, 256, 0, stream>>>(src, dst, L, cursor, epk);
    k_cnt    <<<NGRAPH, 256, 0, stream>>>(mask, gcnt);

    k_mega<<<NBLK, 256, 0, stream>>>(x, mask, W1, b1, bb, gb, betab, g2, beta2, W2, b2,
                                     rowptr, epk, gcnt, Braw, H0, Uh0, Uh1,
                                     sums, gsum, outp, bar);
}

// Round 15
// 812.325 us; speedup vs baseline: 4.8434x; 4.8434x over previous
//
#include <hip/hip_runtime.h>
#include <hip/hip_bf16.h>
#include <math.h>

#define NTOT   32768
#define NPER   4096
#define NGRAPH 8
#define EDGES  262144
#define HCH    128
#define EPSBN  1e-5f
#define BANKS  16
#define SPM_E  256

typedef short bf16x8 __attribute__((ext_vector_type(8)));
typedef float f32x4  __attribute__((ext_vector_type(4)));

__device__ __forceinline__ float eluf(float x){ return x > 0.f ? x : expm1f(x); }
__device__ __forceinline__ ushort f2bf(float f){
    uint u = __float_as_uint(f);
    u += 0x7fffu + ((u >> 16) & 1u);          // round-to-nearest-even
    return (ushort)(u >> 16);
}
__device__ __forceinline__ float bf2f(ushort h){ return __uint_as_float(((uint)h) << 16); }
__device__ __forceinline__ float bfhi(uint p){ return __uint_as_float(p & 0xffff0000u); }
__device__ __forceinline__ float bflo(uint p){ return __uint_as_float(p << 16); }

// ---------------- CSR build ----------------
__global__ __launch_bounds__(256) void k_hist(const int* __restrict__ dst, int* __restrict__ deg){
    int e = blockIdx.x * 256 + threadIdx.x;
    atomicAdd(&deg[dst[e]], 1);
}

__global__ __launch_bounds__(1024) void k_scan(const int* __restrict__ deg, int* __restrict__ rowptr,
                                               int* __restrict__ cursor){
    __shared__ int part[1024];
    int t = threadIdx.x;
    const int chunk = NTOT / 1024;
    int base = t * chunk;
    int s = 0;
    for (int j = 0; j < chunk; ++j) s += deg[base + j];
    part[t] = s; __syncthreads();
    for (int off = 1; off < 1024; off <<= 1){
        int v = (t >= off) ? part[t - off] : 0;
        __syncthreads();
        part[t] += v;
        __syncthreads();
    }
    int run = part[t] - s;
    for (int j = 0; j < chunk; ++j){
        rowptr[base + j] = run; cursor[base + j] = run;
        run += deg[base + j];
    }
    if (t == 1023) rowptr[NTOT] = run;
}

__global__ __launch_bounds__(256) void k_scatter(const int* __restrict__ src, const int* __restrict__ dst,
                                                 const float* __restrict__ L, int* __restrict__ cursor,
                                                 int2* __restrict__ epk){
    int e = blockIdx.x * 256 + threadIdx.x;
    int d = dst[e];
    int pos = atomicAdd(&cursor[d], 1);
    int2 pv; pv.x = src[e]; pv.y = __float_as_int(L[e]);
    epk[pos] = pv;
}

// ---------------- per-graph mask count ----------------
__global__ __launch_bounds__(256) void k_cnt(const float* __restrict__ mask, float* __restrict__ gcnt){
    __shared__ float red[4];
    int g = blockIdx.x, t = threadIdx.x;
    float s = 0.f;
    for (int i = t; i < NPER; i += 256) s += mask[g * NPER + i];
    #pragma unroll
    for (int off = 32; off > 0; off >>= 1) s += __shfl_down(s, off);
    if ((t & 63) == 0) red[t >> 6] = s;
    __syncthreads();
    if (t == 0) gcnt[g] = red[0] + red[1] + red[2] + red[3];
}

// ---------------- one-time: all 30 layers' raw W -> fragment-native bf16 ----------------
__global__ __launch_bounds__(256) void k_wall(const float* __restrict__ Wb, uint4* __restrict__ Braw){
    int layer = blockIdx.x >> 4;
    int it = ((blockIdx.x & 15) << 8) | threadIdx.x;   // 0..4095
    int nt = it >> 9;
    int rem = it & 511;
    int kc = rem >> 6, l = rem & 63;
    int col = nt * 16 + (l & 15);
    int k0  = kc * 32 + (l >> 4) * 8;
    const float* W = Wb + (size_t)layer * 256 * HCH;
    ushort hi[8];
    #pragma unroll
    for (int q = 0; q < 8; ++q) hi[q] = f2bf(W[(size_t)(k0 + q) * HCH + col]);
    uint4 vh;
    vh.x = hi[0] | ((uint)hi[1] << 16); vh.y = hi[2] | ((uint)hi[3] << 16);
    vh.z = hi[4] | ((uint)hi[5] << 16); vh.w = hi[6] | ((uint)hi[7] << 16);
    Braw[(size_t)layer * 4096 + (size_t)(nt * 8 + kc) * 64 + l] = vh;
}

// ---------------- conv1: H = x@W1+b1 ; Uh = bf16(elu(H)) ; banked stats ----------------
__global__ __launch_bounds__(256) void k_conv1(const float* __restrict__ x, const float* __restrict__ W1,
                                               const float* __restrict__ b1, float* __restrict__ H,
                                               ushort* __restrict__ Uh, float* __restrict__ sums0){
    __shared__ float red[2][2][128];
    int t = threadIdx.x, ch = t & 127, pr = t >> 7;
    float w0 = W1[ch], w1 = W1[128 + ch], w2 = W1[256 + ch], bv = b1[ch];
    int base = blockIdx.x * 128;
    float ls = 0.f, lss = 0.f;
    for (int it = 0; it < 64; ++it){
        int row = base + 2 * it + pr;
        const float* xr = x + (size_t)row * 3;
        float h = fmaf(xr[2], w2, fmaf(xr[1], w1, fmaf(xr[0], w0, bv)));
        H[(size_t)row * HCH + ch] = h;
        float u = eluf(h);
        Uh[(size_t)row * HCH + ch] = f2bf(u);
        ls += u; lss += u * u;
    }
    red[0][pr][ch] = ls; red[1][pr][ch] = lss;
    __syncthreads();
    if (t < 128){
        float* sb_ = sums0 + (size_t)(blockIdx.x & (BANKS - 1)) * 512;
        atomicAdd(&sb_[t],       red[0][0][t] + red[0][1][t]);
        atomicAdd(&sb_[256 + t], red[1][0][t] + red[1][1][t]);
    }
}

// ---------------- SpMM: LDS-staged block edge slice + batched-8 gathers ----------------
__global__ __launch_bounds__(256) void k_spmm(const ushort* __restrict__ Uh, const int* __restrict__ rowptr,
                                              const int2* __restrict__ epk,
                                              ushort* __restrict__ AGGh, float* __restrict__ sums_k){
    __shared__ float red[2][16][128];
    __shared__ int2 se[SPM_E];
    __shared__ int  sp[17];
    const int t = threadIdx.x;
    const int rg = t >> 4, c8 = (t & 15) << 3;
    const int bid = blockIdx.x;
    const int sb = ((bid & 7) << 8) | (bid >> 3);   // graph -> XCD; 256 blocks per graph
    const int n0b = sb * 16;
    if (t <= 16) sp[t] = rowptr[n0b + t];
    __syncthreads();
    const int eb = sp[0];
    const int ec = sp[16] - eb;
    for (int i = t; i < ec && i < SPM_E; i += 256) se[i] = epk[eb + i];
    __syncthreads();
    const int node = n0b + rg;
    const int e0 = sp[rg] - eb, e1 = sp[rg + 1] - eb;

    auto acc8 = [](float* a, uint4 p, float wv){
        a[0] = fmaf(bflo(p.x), wv, a[0]); a[1] = fmaf(bfhi(p.x), wv, a[1]);
        a[2] = fmaf(bflo(p.y), wv, a[2]); a[3] = fmaf(bfhi(p.y), wv, a[3]);
        a[4] = fmaf(bflo(p.z), wv, a[4]); a[5] = fmaf(bfhi(p.z), wv, a[5]);
        a[6] = fmaf(bflo(p.w), wv, a[6]); a[7] = fmaf(bfhi(p.w), wv, a[7]);
    };
    auto edge = [&](int e)->int2{
        return (e < SPM_E) ? se[e] : epk[eb + e];
    };

    float a[8] = {0,0,0,0,0,0,0,0};
    int e = e0;
    for (; e + 8 <= e1; e += 8){
        int2 PV[8];
        #pragma unroll
        for (int q = 0; q < 8; ++q) PV[q] = edge(e + q);
        uint4 P[8];
        #pragma unroll
        for (int q = 0; q < 8; ++q)
            P[q] = *(const uint4*)(Uh + (size_t)PV[q].x * HCH + c8);
        #pragma unroll
        for (int q = 0; q < 8; ++q) acc8(a, P[q], __int_as_float(PV[q].y));
    }
    for (; e + 2 <= e1; e += 2){
        int2 pv0 = edge(e), pv1 = edge(e + 1);
        uint4 p0 = *(const uint4*)(Uh + (size_t)pv0.x * HCH + c8);
        uint4 p1 = *(const uint4*)(Uh + (size_t)pv1.x * HCH + c8);
        acc8(a, p0, __int_as_float(pv0.y));
        acc8(a, p1, __int_as_float(pv1.y));
    }
    if (e < e1){
        int2 pv = edge(e);
        uint4 p = *(const uint4*)(Uh + (size_t)pv.x * HCH + c8);
        acc8(a, p, __int_as_float(pv.y));
    }
    uint4 o;
    o.x = (uint)f2bf(a[0]) | ((uint)f2bf(a[1]) << 16);
    o.y = (uint)f2bf(a[2]) | ((uint)f2bf(a[3]) << 16);
    o.z = (uint)f2bf(a[4]) | ((uint)f2bf(a[5]) << 16);
    o.w = (uint)f2bf(a[6]) | ((uint)f2bf(a[7]) << 16);
    *(uint4*)(AGGh + (size_t)node * HCH + c8) = o;

    #pragma unroll
    for (int j = 0; j < 8; ++j){
        red[0][rg][c8 + j] = a[j];
        red[1][rg][c8 + j] = a[j] * a[j];
    }
    __syncthreads();
    if (t < 128){
        float s = 0.f, q = 0.f;
        #pragma unroll
        for (int g = 0; g < 16; ++g){ s += red[0][g][t]; q += red[1][g][t]; }
        float* sb_ = sums_k + (size_t)(bid & (BANKS - 1)) * 512;
        atomicAdd(&sb_[128 + t], s);
        atomicAdd(&sb_[384 + t], q);
    }
}

// ---------------- MFMA GEMM (bf16 activations): BN folded into A at staging ----------------
template<int MODE, int RES>
__global__ __launch_bounds__(256) void k_gemm(
        const ushort* __restrict__ Uh, const ushort* __restrict__ AGGh,
        const uint4* __restrict__ Braw,
        const float* __restrict__ gamma, const float* __restrict__ beta,
        const float* __restrict__ bias,
        const float* __restrict__ sums_k, const float* __restrict__ gsum_k,
        const float* __restrict__ gcnt,
        const float* __restrict__ Hres, float* __restrict__ Hout,
        ushort* __restrict__ Uhout,
        float* __restrict__ sums_n, const float* __restrict__ mask,
        float* __restrict__ gsum_next)
{
    __shared__ ushort a_sm[4][2][512];        // per-wave 2x1KB dbuf (16 rows x 32 ch bf16)
    __shared__ float s_s[256], s_sh[256];
    __shared__ uint s_avgpk[64];              // MODE1 broadcast agg row, packed bf16 pairs
    __shared__ float red[2][2][128];
    __shared__ float gred[2][128];
    const int t = threadIdx.x;
    const int w = t >> 6, lane = t & 63;
    const int rlo = lane & 15, kg = lane >> 4;
    const int bid = blockIdx.x;
    const int sb  = ((bid & 7) << 7) | (bid >> 3);   // graph -> XCD
    const int row0 = sb * 32;
    const int wr0 = row0 + (w & 1) * 16;
    const int colbase = (w >> 1) * 64;
    const int ntb = (w >> 1) * 4;

    // ---- prologue: per-block BN affine ----
    {
        float m, ex2;
        if (MODE == 1 && t >= 128){
            float S1 = 0.f, S2 = 0.f;
            #pragma unroll
            for (int g = 0; g < NGRAPH; ++g){
                float a = gsum_k[g * 128 + (t - 128)] / gcnt[g];
                S1 += a; S2 += a * a;
            }
            m = S1 * (1.f / NGRAPH); ex2 = S2 * (1.f / NGRAPH);
        } else {
            float S = 0.f, Q = 0.f;
            #pragma unroll
            for (int b = 0; b < BANKS; ++b){
                S += sums_k[(size_t)b * 512 + t];
                Q += sums_k[(size_t)b * 512 + 256 + t];
            }
            m = S * (1.f / NTOT); ex2 = Q * (1.f / NTOT);
        }
        float var = ex2 - m * m;
        float sc = gamma[t] * rsqrtf(var + EPSBN);
        s_s[t] = sc; s_sh[t] = beta[t] - m * sc;
    }
    __syncthreads();
    if (MODE == 1){
        if (t < 64){
            int g0 = row0 >> 12;
            float a0 = gsum_k[g0 * 128 + 2 * t]     / gcnt[g0];
            float a1 = gsum_k[g0 * 128 + 2 * t + 1] / gcnt[g0];
            float z0 = fmaf(a0, s_s[128 + 2 * t],     s_sh[128 + 2 * t]);
            float z1 = fmaf(a1, s_s[128 + 2 * t + 1], s_sh[128 + 2 * t + 1]);
            s_avgpk[t] = (uint)f2bf(z0) | ((uint)f2bf(z1) << 16);
        }
        __syncthreads();
    }

    // stage 16 rows x 32 ch of normalized bf16; swizzle slot = sl ^ ((row>>1)&3)
    auto stage = [&](int kc, ushort* dst){
        int row = lane >> 2, sl = lane & 3;
        int ch = kc * 32 + sl * 8;
        const ushort* sp = (ch < 128)
            ? (Uh   + (size_t)(wr0 + row) * HCH + ch)
            : (AGGh + (size_t)(wr0 + row) * HCH + (ch - 128));
        uint4 v = *(const uint4*)sp;
        uint in[4] = {v.x, v.y, v.z, v.w};
        uint o[4];
        #pragma unroll
        for (int j = 0; j < 4; ++j){
            int c = ch + 2 * j;
            float z0 = fmaf(bflo(in[j]), s_s[c],     s_sh[c]);
            float z1 = fmaf(bfhi(in[j]), s_s[c + 1], s_sh[c + 1]);
            o[j] = (uint)f2bf(z0) | ((uint)f2bf(z1) << 16);
        }
        int slot = sl ^ ((row >> 1) & 3);
        uint4 wv = {o[0], o[1], o[2], o[3]};
        *(uint4*)&dst[row * 32 + slot * 8] = wv;
    };

    f32x4 acc[4];
    #pragma unroll
    for (int n = 0; n < 4; ++n) acc[n] = (f32x4){0.f, 0.f, 0.f, 0.f};

    stage(0, &a_sm[w][0][0]);
    #pragma unroll
    for (int kc = 0; kc < 8; ++kc){
        ushort* cur = &a_sm[w][kc & 1][0];
        ushort* nxt = &a_sm[w][(kc & 1) ^ 1][0];
        union { uint u[4]; bf16x8 v; } ah;
        if (MODE == 1 && kc >= 4){
            int base = (kc - 4) * 16 + kg * 4;
            ah.u[0] = s_avgpk[base + 0]; ah.u[1] = s_avgpk[base + 1];
            ah.u[2] = s_avgpk[base + 2]; ah.u[3] = s_avgpk[base + 3];
        } else {
            int slot = kg ^ ((rlo >> 1) & 3);
            uint4 c0 = *(const uint4*)&cur[rlo * 32 + slot * 8];
            ah.u[0] = c0.x; ah.u[1] = c0.y; ah.u[2] = c0.z; ah.u[3] = c0.w;
        }
        if (kc + 1 < ((MODE == 1) ? 4 : 8)) stage(kc + 1, nxt);
        #pragma unroll
        for (int n = 0; n < 4; ++n){
            const int nt = ntb + n;
            union { uint4 q; bf16x8 v; } bh;
            bh.q = Braw[(size_t)(nt * 8 + kc) * 64 + lane];
            acc[n] = __builtin_amdgcn_mfma_f32_16x16x32_bf16(ah.v, bh.v, acc[n], 0, 0, 0);
        }
    }

    // epilogue: bias (+res) -> h ; u = elu(h) ; bf16 store ; shfl-reduced stats
    const int r0 = wr0 + kg * 4;
    float mk[4] = {0.f, 0.f, 0.f, 0.f};
    if (gsum_next){ mk[0] = mask[r0]; mk[1] = mask[r0+1]; mk[2] = mask[r0+2]; mk[3] = mask[r0+3]; }
    #pragma unroll
    for (int n = 0; n < 4; ++n){
        const int c = colbase + n * 16 + rlo;
        const float bc = bias[c];
        float s = 0.f, q = 0.f, g = 0.f;
        #pragma unroll
        for (int r = 0; r < 4; ++r){
            int row = r0 + r;
            float h = acc[n][r] + bc;
            if (RES){
                h += Hres[(size_t)row * HCH + c];
                Hout[(size_t)row * HCH + c] = h;
            }
            float u = eluf(h);
            Uhout[(size_t)row * HCH + c] = f2bf(u);
            s += u; q += u * u;
            if (gsum_next) g = fmaf(u, mk[r], g);
        }
        s += __shfl_xor(s, 16); s += __shfl_xor(s, 32);
        q += __shfl_xor(q, 16); q += __shfl_xor(q, 32);
        if (gsum_next){ g += __shfl_xor(g, 16); g += __shfl_xor(g, 32); }
        if (kg == 0){
            red[0][w & 1][c] = s;
            red[1][w & 1][c] = q;
            if (gsum_next) gred[w & 1][c] = g;
        }
    }
    __syncthreads();
    if (t < 128){
        float a = red[0][0][t] + red[0][1][t];
        float b = red[1][0][t] + red[1][1][t];
        float* sb_ = sums_n + (size_t)(bid & (BANKS - 1)) * 512;
        atomicAdd(&sb_[t], a);
        atomicAdd(&sb_[256 + t], b);
        if (gsum_next)
            atomicAdd(&gsum_next[(row0 >> 12) * 128 + t], gred[0][t] + gred[1][t]);
    }
}

// ---------------- final: BN(elu(h)) @ W2 + b2 + x[:, :1] (banked stats) ----------------
__global__ __launch_bounds__(256) void k_final(const ushort* __restrict__ Uh, const float* __restrict__ sums30,
                                               const float* __restrict__ g2, const float* __restrict__ beta2,
                                               const float* __restrict__ W2, const float* __restrict__ b2,
                                               const float* __restrict__ x, float* __restrict__ out){
    __shared__ float s_s[128], s_sh[128];
    __shared__ float wred[4];
    int t = threadIdx.x;
    if (t < 128){
        float S = 0.f, Q = 0.f;
        for (int b = 0; b < BANKS; ++b){
            S += sums30[(size_t)b * 512 + t];
            Q += sums30[(size_t)b * 512 + 256 + t];
        }
        float m   = S * (1.f / NTOT);
        float ex2 = Q * (1.f / NTOT);
        float var = ex2 - m * m;
        float sc = g2[t] * rsqrtf(var + EPSBN);
        s_s[t] = sc; s_sh[t] = beta2[t] - m * sc;
    }
    __syncthreads();
    int lane = t & 63, wid = t >> 6;
    int ch = t & 127, pr = t >> 7;
    float w2 = W2[ch];
    float b2v = b2[0];
    int base = blockIdx.x * 64;
    for (int it = 0; it < 32; ++it){
        int rowa = base + it * 2;
        int row  = rowa + pr;
        float u = bf2f(Uh[(size_t)row * HCH + ch]);
        float v = (u * s_s[ch] + s_sh[ch]) * w2;
        #pragma unroll
        for (int off = 32; off > 0; off >>= 1) v += __shfl_down(v, off);
        if (lane == 0) wred[wid] = v;
        __syncthreads();
        if (t == 0)   out[rowa]     = wred[0] + wred[1] + b2v + x[(size_t)rowa * 3];
        if (t == 128) out[rowa + 1] = wred[2] + wred[3] + b2v + x[(size_t)(rowa + 1) * 3];
        __syncthreads();
    }
}

// ---------------- host ----------------
extern "C" void kernel_launch(void* const* d_in, const int* in_sizes, int n_in,
                              void* d_out, int out_size, void* d_ws, size_t ws_size,
                              hipStream_t stream){
    const float* x    = (const float*)d_in[0];
    const float* L    = (const float*)d_in[1];
    const float* mask = (const float*)d_in[2];
    const float* W1   = (const float*)d_in[3];
    const float* b1   = (const float*)d_in[4];
    const float* Wb   = (const float*)d_in[5];
    const float* bb   = (const float*)d_in[6];
    const float* gb   = (const float*)d_in[7];
    const float* betab= (const float*)d_in[8];
    const float* g2   = (const float*)d_in[9];
    const float* beta2= (const float*)d_in[10];
    const float* W2   = (const float*)d_in[11];
    const float* b2   = (const float*)d_in[12];
    const int*   src  = (const int*)d_in[13];
    const int*   dst  = (const int*)d_in[14];

    char* base = (char*)d_ws;
    size_t off = 0;
    auto alloc = [&](size_t bytes)->char*{
        char* r = base + off;
        off = (off + bytes + 255) & ~(size_t)255;
        return r;
    };
    float* sums  = (float*)alloc((size_t)31 * BANKS * 512 * sizeof(float));  // banked BN stats
    float* gsum  = (float*)alloc(30 * NGRAPH * HCH * sizeof(float));
    int*   deg   = (int*)  alloc(NTOT * sizeof(int));
    size_t zero_bytes = off;                                       // zeroed once per launch
    float* gcnt  = (float*)alloc(NGRAPH * sizeof(float));
    int*   cursor= (int*)  alloc(NTOT * sizeof(int));
    int*   rowptr= (int*)  alloc((NTOT + 1) * sizeof(int));
    int2*  epk   = (int2*) alloc(EDGES * sizeof(int2));
    float* H0    = (float*)alloc((size_t)NTOT * HCH * sizeof(float));
    ushort* Uh0  = (ushort*)alloc((size_t)NTOT * HCH * sizeof(ushort));
    ushort* Uh1  = (ushort*)alloc((size_t)NTOT * HCH * sizeof(ushort));
    ushort* AGGh = (ushort*)alloc((size_t)NTOT * HCH * sizeof(ushort));
    uint4* Braw  = (uint4*)alloc((size_t)30 * 4096 * sizeof(uint4));   // 1.97 MB raw-W fragments
    (void)ws_size; (void)in_sizes; (void)n_in; (void)out_size;

    hipMemsetAsync(d_ws, 0, zero_bytes, stream);
    k_wall   <<<480, 256, 0, stream>>>(Wb, Braw);
    k_hist   <<<EDGES / 256, 256, 0, stream>>>(dst, deg);
    k_scan   <<<1, 1024, 0, stream>>>(deg, rowptr, cursor);
    k_scatter<<<EDGES / 256, 256, 0, stream>>>(src, dst, L, cursor, epk);
    k_cnt    <<<NGRAPH, 256, 0, stream>>>(mask, gcnt);
    k_conv1  <<<NTOT / 128, 256, 0, stream>>>(x, W1, b1, H0, Uh0, sums);

    ushort* Ucur = Uh0; ushort* Unext = Uh1;
    for (int i = 0; i < 15; ++i){
        for (int j = 0; j < 2; ++j){
            int k = 2 * i + j;
            const uint4* Bk  = Braw + (size_t)k * 4096;
            const float* bk  = bb + (size_t)k * HCH;
            const float* gk  = gb + (size_t)k * 256;
            const float* bek = betab + (size_t)k * 256;
            float* sk = sums + (size_t)k * BANKS * 512;
            float* sn = sums + (size_t)(k + 1) * BANKS * 512;
            bool nextg  = (k < 29) && ((((k + 1) / 2) & 1) == 1);
            float* gsn = nextg ? (gsum + (size_t)(k + 1) * NGRAPH * HCH) : nullptr;
            if ((i & 1) == 0){
                k_spmm<<<NTOT / 16, 256, 0, stream>>>(Ucur, rowptr, epk, AGGh, sk);
                if (j == 0)
                    k_gemm<0,0><<<NTOT / 32, 256, 0, stream>>>(Ucur, AGGh, Bk, gk, bek, bk,
                                                               sk, nullptr, gcnt,
                                                               nullptr, nullptr, Unext, sn, mask, gsn);
                else
                    k_gemm<0,1><<<NTOT / 32, 256, 0, stream>>>(Ucur, AGGh, Bk, gk, bek, bk,
                                                               sk, nullptr, gcnt,
                                                               H0, H0, Unext, sn, mask, gsn);
            } else {
                float* gs = gsum + (size_t)k * NGRAPH * HCH;
                if (j == 0)
                    k_gemm<1,0><<<NTOT / 32, 256, 0, stream>>>(Ucur, nullptr, Bk, gk, bek, bk,
                                                               sk, gs, gcnt,
                                                               nullptr, nullptr, Unext, sn, mask, gsn);
                else
                    k_gemm<1,1><<<NTOT / 32, 256, 0, stream>>>(Ucur, nullptr, Bk, gk, bek, bk,
                                                               sk, gs, gcnt,
                                                               H0, H0, Unext, sn, mask, gsn);
            }
            ushort* tmp = Ucur; Ucur = Unext; Unext = tmp;
        }
    }
    k_final<<<NTOT / 64, 256, 0, stream>>>(Ucur, sums + (size_t)30 * BANKS * 512, g2, beta2, W2, b2, x, (float*)d_out);
}

// Round 16
// 771.903 us; speedup vs baseline: 5.0971x; 1.0524x over previous
//
#include <hip/hip_runtime.h>
#include <hip/hip_bf16.h>
#include <math.h>

#define NTOT   32768
#define NPER   4096
#define NGRAPH 8
#define EDGES  262144
#define HCH    128
#define EPSBN  1e-5f
#define BANKS  16

typedef short bf16x8 __attribute__((ext_vector_type(8)));
typedef float f32x4  __attribute__((ext_vector_type(4)));

__device__ __forceinline__ float eluf(float x){ return x > 0.f ? x : expm1f(x); }
__device__ __forceinline__ ushort f2bf(float f){
    uint u = __float_as_uint(f);
    u += 0x7fffu + ((u >> 16) & 1u);          // round-to-nearest-even
    return (ushort)(u >> 16);
}
__device__ __forceinline__ float bf2f(ushort h){ return __uint_as_float(((uint)h) << 16); }
__device__ __forceinline__ float bfhi(uint p){ return __uint_as_float(p & 0xffff0000u); }
__device__ __forceinline__ float bflo(uint p){ return __uint_as_float(p << 16); }

// ---------------- CSR build ----------------
__global__ __launch_bounds__(256) void k_hist(const int* __restrict__ dst, int* __restrict__ deg){
    int e = blockIdx.x * 256 + threadIdx.x;
    atomicAdd(&deg[dst[e]], 1);
}

__global__ __launch_bounds__(1024) void k_scan(const int* __restrict__ deg, int* __restrict__ rowptr,
                                               int* __restrict__ cursor){
    __shared__ int part[1024];
    int t = threadIdx.x;
    const int chunk = NTOT / 1024;
    int base = t * chunk;
    int s = 0;
    for (int j = 0; j < chunk; ++j) s += deg[base + j];
    part[t] = s; __syncthreads();
    for (int off = 1; off < 1024; off <<= 1){
        int v = (t >= off) ? part[t - off] : 0;
        __syncthreads();
        part[t] += v;
        __syncthreads();
    }
    int run = part[t] - s;
    for (int j = 0; j < chunk; ++j){
        rowptr[base + j] = run; cursor[base + j] = run;
        run += deg[base + j];
    }
    if (t == 1023) rowptr[NTOT] = run;
}

__global__ __launch_bounds__(256) void k_scatter(const int* __restrict__ src, const int* __restrict__ dst,
                                                 const float* __restrict__ L, int* __restrict__ cursor,
                                                 int2* __restrict__ epk){
    int e = blockIdx.x * 256 + threadIdx.x;
    int d = dst[e];
    int pos = atomicAdd(&cursor[d], 1);
    int2 pv; pv.x = src[e]; pv.y = __float_as_int(L[e]);
    epk[pos] = pv;
}

// ---------------- per-graph mask count ----------------
__global__ __launch_bounds__(256) void k_cnt(const float* __restrict__ mask, float* __restrict__ gcnt){
    __shared__ float red[4];
    int g = blockIdx.x, t = threadIdx.x;
    float s = 0.f;
    for (int i = t; i < NPER; i += 256) s += mask[g * NPER + i];
    #pragma unroll
    for (int off = 32; off > 0; off >>= 1) s += __shfl_down(s, off);
    if ((t & 63) == 0) red[t >> 6] = s;
    __syncthreads();
    if (t == 0) gcnt[g] = red[0] + red[1] + red[2] + red[3];
}

// ---------------- one-time: all 30 layers' raw W -> fragment-native bf16 ----------------
__global__ __launch_bounds__(256) void k_wall(const float* __restrict__ Wb, uint4* __restrict__ Braw){
    int layer = blockIdx.x >> 4;
    int it = ((blockIdx.x & 15) << 8) | threadIdx.x;   // 0..4095
    int nt = it >> 9;
    int rem = it & 511;
    int kc = rem >> 6, l = rem & 63;
    int col = nt * 16 + (l & 15);
    int k0  = kc * 32 + (l >> 4) * 8;
    const float* W = Wb + (size_t)layer * 256 * HCH;
    ushort hi[8];
    #pragma unroll
    for (int q = 0; q < 8; ++q) hi[q] = f2bf(W[(size_t)(k0 + q) * HCH + col]);
    uint4 vh;
    vh.x = hi[0] | ((uint)hi[1] << 16); vh.y = hi[2] | ((uint)hi[3] << 16);
    vh.z = hi[4] | ((uint)hi[5] << 16); vh.w = hi[6] | ((uint)hi[7] << 16);
    Braw[(size_t)layer * 4096 + (size_t)(nt * 8 + kc) * 64 + l] = vh;
}

// ---------------- conv1: H = x@W1+b1 ; Uh = bf16(elu(H)) ; banked stats ----------------
__global__ __launch_bounds__(256) void k_conv1(const float* __restrict__ x, const float* __restrict__ W1,
                                               const float* __restrict__ b1, float* __restrict__ H,
                                               ushort* __restrict__ Uh, float* __restrict__ sums0){
    __shared__ float red[2][2][128];
    int t = threadIdx.x, ch = t & 127, pr = t >> 7;
    float w0 = W1[ch], w1 = W1[128 + ch], w2 = W1[256 + ch], bv = b1[ch];
    int base = blockIdx.x * 128;
    float ls = 0.f, lss = 0.f;
    for (int it = 0; it < 64; ++it){
        int row = base + 2 * it + pr;
        const float* xr = x + (size_t)row * 3;
        float h = fmaf(xr[2], w2, fmaf(xr[1], w1, fmaf(xr[0], w0, bv)));
        H[(size_t)row * HCH + ch] = h;
        float u = eluf(h);
        Uh[(size_t)row * HCH + ch] = f2bf(u);
        ls += u; lss += u * u;
    }
    red[0][pr][ch] = ls; red[1][pr][ch] = lss;
    __syncthreads();
    if (t < 128){
        float* sb_ = sums0 + (size_t)(blockIdx.x & (BANKS - 1)) * 512;
        atomicAdd(&sb_[t],       red[0][0][t] + red[0][1][t]);
        atomicAdd(&sb_[256 + t], red[1][0][t] + red[1][1][t]);
    }
}

// ---------------- SpMM: 1 node / 16-lane group, 2048 blocks, batched-8 gather ----------------
__global__ __launch_bounds__(256) void k_spmm(const ushort* __restrict__ Uh, const int* __restrict__ rowptr,
                                              const int2* __restrict__ epk,
                                              ushort* __restrict__ AGGh, float* __restrict__ sums_k){
    __shared__ float red[2][16][128];
    const int t = threadIdx.x;
    const int rg = t >> 4, c8 = (t & 15) << 3;
    const int bid = blockIdx.x;
    const int sb = ((bid & 7) << 8) | (bid >> 3);   // graph -> XCD; 256 blocks per graph
    const int node = sb * 16 + rg;
    const int e0 = rowptr[node], e1 = rowptr[node + 1];

    auto acc8 = [](float* a, uint4 p, float wv){
        a[0] = fmaf(bflo(p.x), wv, a[0]); a[1] = fmaf(bfhi(p.x), wv, a[1]);
        a[2] = fmaf(bflo(p.y), wv, a[2]); a[3] = fmaf(bfhi(p.y), wv, a[3]);
        a[4] = fmaf(bflo(p.z), wv, a[4]); a[5] = fmaf(bfhi(p.z), wv, a[5]);
        a[6] = fmaf(bflo(p.w), wv, a[6]); a[7] = fmaf(bfhi(p.w), wv, a[7]);
    };

    float a[8] = {0,0,0,0,0,0,0,0};
    int e = e0;
    for (; e + 8 <= e1; e += 8){
        int2 PV[8];
        #pragma unroll
        for (int q = 0; q < 8; ++q) PV[q] = epk[e + q];
        uint4 P[8];
        #pragma unroll
        for (int q = 0; q < 8; ++q)
            P[q] = *(const uint4*)(Uh + (size_t)PV[q].x * HCH + c8);
        #pragma unroll
        for (int q = 0; q < 8; ++q) acc8(a, P[q], __int_as_float(PV[q].y));
    }
    for (; e + 2 <= e1; e += 2){
        int2 pv0 = epk[e], pv1 = epk[e + 1];
        uint4 p0 = *(const uint4*)(Uh + (size_t)pv0.x * HCH + c8);
        uint4 p1 = *(const uint4*)(Uh + (size_t)pv1.x * HCH + c8);
        acc8(a, p0, __int_as_float(pv0.y));
        acc8(a, p1, __int_as_float(pv1.y));
    }
    if (e < e1){
        int2 pv = epk[e];
        uint4 p = *(const uint4*)(Uh + (size_t)pv.x * HCH + c8);
        acc8(a, p, __int_as_float(pv.y));
    }
    uint4 o;
    o.x = (uint)f2bf(a[0]) | ((uint)f2bf(a[1]) << 16);
    o.y = (uint)f2bf(a[2]) | ((uint)f2bf(a[3]) << 16);
    o.z = (uint)f2bf(a[4]) | ((uint)f2bf(a[5]) << 16);
    o.w = (uint)f2bf(a[6]) | ((uint)f2bf(a[7]) << 16);
    *(uint4*)(AGGh + (size_t)node * HCH + c8) = o;

    #pragma unroll
    for (int j = 0; j < 8; ++j){
        red[0][rg][c8 + j] = a[j];
        red[1][rg][c8 + j] = a[j] * a[j];
    }
    __syncthreads();
    if (t < 128){
        float s = 0.f, q = 0.f;
        #pragma unroll
        for (int g = 0; g < 16; ++g){ s += red[0][g][t]; q += red[1][g][t]; }
        float* sb_ = sums_k + (size_t)(bid & (BANKS - 1)) * 512;
        atomicAdd(&sb_[128 + t], s);
        atomicAdd(&sb_[384 + t], q);
    }
}

// ---------------- MFMA GEMM (bf16 activations): BN folded into A at staging ----------------
template<int MODE, int RES>
__global__ __launch_bounds__(256) void k_gemm(
        const ushort* __restrict__ Uh, const ushort* __restrict__ AGGh,
        const uint4* __restrict__ Braw,
        const float* __restrict__ gamma, const float* __restrict__ beta,
        const float* __restrict__ bias,
        const float* __restrict__ sums_k, const float* __restrict__ gsum_k,
        const float* __restrict__ gcnt,
        const float* __restrict__ Hres, float* __restrict__ Hout,
        ushort* __restrict__ Uhout,
        float* __restrict__ sums_n, const float* __restrict__ mask,
        float* __restrict__ gsum_next)
{
    __shared__ ushort a_sm[4][2][512];        // per-wave 2x1KB dbuf (16 rows x 32 ch bf16)
    __shared__ float s_s[256], s_sh[256];
    __shared__ uint s_avgpk[64];              // MODE1 broadcast agg row, packed bf16 pairs
    __shared__ float red[2][2][128];
    __shared__ float gred[2][128];
    const int t = threadIdx.x;
    const int w = t >> 6, lane = t & 63;
    const int rlo = lane & 15, kg = lane >> 4;
    const int bid = blockIdx.x;
    const int sb  = ((bid & 7) << 7) | (bid >> 3);   // graph -> XCD
    const int row0 = sb * 32;
    const int wr0 = row0 + (w & 1) * 16;
    const int colbase = (w >> 1) * 64;
    const int ntb = (w >> 1) * 4;

    // ---- prologue: per-block BN affine ----
    {
        float m, ex2;
        if (MODE == 1 && t >= 128){
            float S1 = 0.f, S2 = 0.f;
            #pragma unroll
            for (int g = 0; g < NGRAPH; ++g){
                float a = gsum_k[g * 128 + (t - 128)] / gcnt[g];
                S1 += a; S2 += a * a;
            }
            m = S1 * (1.f / NGRAPH); ex2 = S2 * (1.f / NGRAPH);
        } else {
            float S = 0.f, Q = 0.f;
            #pragma unroll
            for (int b = 0; b < BANKS; ++b){
                S += sums_k[(size_t)b * 512 + t];
                Q += sums_k[(size_t)b * 512 + 256 + t];
            }
            m = S * (1.f / NTOT); ex2 = Q * (1.f / NTOT);
        }
        float var = ex2 - m * m;
        float sc = gamma[t] * rsqrtf(var + EPSBN);
        s_s[t] = sc; s_sh[t] = beta[t] - m * sc;
    }
    __syncthreads();
    if (MODE == 1){
        if (t < 64){
            int g0 = row0 >> 12;
            float a0 = gsum_k[g0 * 128 + 2 * t]     / gcnt[g0];
            float a1 = gsum_k[g0 * 128 + 2 * t + 1] / gcnt[g0];
            float z0 = fmaf(a0, s_s[128 + 2 * t],     s_sh[128 + 2 * t]);
            float z1 = fmaf(a1, s_s[128 + 2 * t + 1], s_sh[128 + 2 * t + 1]);
            s_avgpk[t] = (uint)f2bf(z0) | ((uint)f2bf(z1) << 16);
        }
        __syncthreads();
    }

    // stage 16 rows x 32 ch of normalized bf16; swizzle slot = sl ^ ((row>>1)&3)
    auto stage = [&](int kc, ushort* dst){
        int row = lane >> 2, sl = lane & 3;
        int ch = kc * 32 + sl * 8;
        const ushort* sp = (ch < 128)
            ? (Uh   + (size_t)(wr0 + row) * HCH + ch)
            : (AGGh + (size_t)(wr0 + row) * HCH + (ch - 128));
        uint4 v = *(const uint4*)sp;
        uint in[4] = {v.x, v.y, v.z, v.w};
        uint o[4];
        #pragma unroll
        for (int j = 0; j < 4; ++j){
            int c = ch + 2 * j;
            float z0 = fmaf(bflo(in[j]), s_s[c],     s_sh[c]);
            float z1 = fmaf(bfhi(in[j]), s_s[c + 1], s_sh[c + 1]);
            o[j] = (uint)f2bf(z0) | ((uint)f2bf(z1) << 16);
        }
        int slot = sl ^ ((row >> 1) & 3);
        uint4 wv = {o[0], o[1], o[2], o[3]};
        *(uint4*)&dst[row * 32 + slot * 8] = wv;
    };

    f32x4 acc[4];
    #pragma unroll
    for (int n = 0; n < 4; ++n) acc[n] = (f32x4){0.f, 0.f, 0.f, 0.f};

    stage(0, &a_sm[w][0][0]);
    #pragma unroll
    for (int kc = 0; kc < 8; ++kc){
        ushort* cur = &a_sm[w][kc & 1][0];
        ushort* nxt = &a_sm[w][(kc & 1) ^ 1][0];
        union { uint u[4]; bf16x8 v; } ah;
        if (MODE == 1 && kc >= 4){
            int base = (kc - 4) * 16 + kg * 4;
            ah.u[0] = s_avgpk[base + 0]; ah.u[1] = s_avgpk[base + 1];
            ah.u[2] = s_avgpk[base + 2]; ah.u[3] = s_avgpk[base + 3];
        } else {
            int slot = kg ^ ((rlo >> 1) & 3);
            uint4 c0 = *(const uint4*)&cur[rlo * 32 + slot * 8];
            ah.u[0] = c0.x; ah.u[1] = c0.y; ah.u[2] = c0.z; ah.u[3] = c0.w;
        }
        if (kc + 1 < ((MODE == 1) ? 4 : 8)) stage(kc + 1, nxt);
        #pragma unroll
        for (int n = 0; n < 4; ++n){
            const int nt = ntb + n;
            union { uint4 q; bf16x8 v; } bh;
            bh.q = Braw[(size_t)(nt * 8 + kc) * 64 + lane];
            acc[n] = __builtin_amdgcn_mfma_f32_16x16x32_bf16(ah.v, bh.v, acc[n], 0, 0, 0);
        }
    }

    // epilogue: bias (+res) -> h ; u = elu(h) ; bf16 store ; shfl-reduced stats
    const int r0 = wr0 + kg * 4;
    float mk[4] = {0.f, 0.f, 0.f, 0.f};
    if (gsum_next){ mk[0] = mask[r0]; mk[1] = mask[r0+1]; mk[2] = mask[r0+2]; mk[3] = mask[r0+3]; }
    #pragma unroll
    for (int n = 0; n < 4; ++n){
        const int c = colbase + n * 16 + rlo;
        const float bc = bias[c];
        float s = 0.f, q = 0.f, g = 0.f;
        #pragma unroll
        for (int r = 0; r < 4; ++r){
            int row = r0 + r;
            float h = acc[n][r] + bc;
            if (RES){
                h += Hres[(size_t)row * HCH + c];
                Hout[(size_t)row * HCH + c] = h;
            }
            float u = eluf(h);
            Uhout[(size_t)row * HCH + c] = f2bf(u);
            s += u; q += u * u;
            if (gsum_next) g = fmaf(u, mk[r], g);
        }
        s += __shfl_xor(s, 16); s += __shfl_xor(s, 32);
        q += __shfl_xor(q, 16); q += __shfl_xor(q, 32);
        if (gsum_next){ g += __shfl_xor(g, 16); g += __shfl_xor(g, 32); }
        if (kg == 0){
            red[0][w & 1][c] = s;
            red[1][w & 1][c] = q;
            if (gsum_next) gred[w & 1][c] = g;
        }
    }
    __syncthreads();
    if (t < 128){
        float a = red[0][0][t] + red[0][1][t];
        float b = red[1][0][t] + red[1][1][t];
        float* sb_ = sums_n + (size_t)(bid & (BANKS - 1)) * 512;
        atomicAdd(&sb_[t], a);
        atomicAdd(&sb_[256 + t], b);
        if (gsum_next)
            atomicAdd(&gsum_next[(row0 >> 12) * 128 + t], gred[0][t] + gred[1][t]);
    }
}

// ---------------- final: BN(elu(h)) @ W2 + b2 + x[:, :1] (banked stats) ----------------
__global__ __launch_bounds__(256) void k_final(const ushort* __restrict__ Uh, const float* __restrict__ sums30,
                                               const float* __restrict__ g2, const float* __restrict__ beta2,
                                               const float* __restrict__ W2, const float* __restrict__ b2,
                                               const float* __restrict__ x, float* __restrict__ out){
    __shared__ float s_s[128], s_sh[128];
    __shared__ float wred[4];
    int t = threadIdx.x;
    if (t < 128){
        float S = 0.f, Q = 0.f;
        for (int b = 0; b < BANKS; ++b){
            S += sums30[(size_t)b * 512 + t];
            Q += sums30[(size_t)b * 512 + 256 + t];
        }
        float m   = S * (1.f / NTOT);
        float ex2 = Q * (1.f / NTOT);
        float var = ex2 - m * m;
        float sc = g2[t] * rsqrtf(var + EPSBN);
        s_s[t] = sc; s_sh[t] = beta2[t] - m * sc;
    }
    __syncthreads();
    int lane = t & 63, wid = t >> 6;
    int ch = t & 127, pr = t >> 7;
    float w2 = W2[ch];
    float b2v = b2[0];
    int base = blockIdx.x * 64;
    for (int it = 0; it < 32; ++it){
        int rowa = base + it * 2;
        int row  = rowa + pr;
        float u = bf2f(Uh[(size_t)row * HCH + ch]);
        float v = (u * s_s[ch] + s_sh[ch]) * w2;
        #pragma unroll
        for (int off = 32; off > 0; off >>= 1) v += __shfl_down(v, off);
        if (lane == 0) wred[wid] = v;
        __syncthreads();
        if (t == 0)   out[rowa]     = wred[0] + wred[1] + b2v + x[(size_t)rowa * 3];
        if (t == 128) out[rowa + 1] = wred[2] + wred[3] + b2v + x[(size_t)(rowa + 1) * 3];
        __syncthreads();
    }
}

// ---------------- host ----------------
extern "C" void kernel_launch(void* const* d_in, const int* in_sizes, int n_in,
                              void* d_out, int out_size, void* d_ws, size_t ws_size,
                              hipStream_t stream){
    const float* x    = (const float*)d_in[0];
    const float* L    = (const float*)d_in[1];
    const float* mask = (const float*)d_in[2];
    const float* W1   = (const float*)d_in[3];
    const float* b1   = (const float*)d_in[4];
    const float* Wb   = (const float*)d_in[5];
    const float* bb   = (const float*)d_in[6];
    const float* gb   = (const float*)d_in[7];
    const float* betab= (const float*)d_in[8];
    const float* g2   = (const float*)d_in[9];
    const float* beta2= (const float*)d_in[10];
    const float* W2   = (const float*)d_in[11];
    const float* b2   = (const float*)d_in[12];
    const int*   src  = (const int*)d_in[13];
    const int*   dst  = (const int*)d_in[14];

    char* base = (char*)d_ws;
    size_t off = 0;
    auto alloc = [&](size_t bytes)->char*{
        char* r = base + off;
        off = (off + bytes + 255) & ~(size_t)255;
        return r;
    };
    float* sums  = (float*)alloc((size_t)31 * BANKS * 512 * sizeof(float));  // banked BN stats
    float* gsum  = (float*)alloc(30 * NGRAPH * HCH * sizeof(float));
    int*   deg   = (int*)  alloc(NTOT * sizeof(int));
    size_t zero_bytes = off;                                       // zeroed once per launch
    float* gcnt  = (float*)alloc(NGRAPH * sizeof(float));
    int*   cursor= (int*)  alloc(NTOT * sizeof(int));
    int*   rowptr= (int*)  alloc((NTOT + 1) * sizeof(int));
    int2*  epk   = (int2*) alloc(EDGES * sizeof(int2));
    float* H0    = (float*)alloc((size_t)NTOT * HCH * sizeof(float));
    ushort* Uh0  = (ushort*)alloc((size_t)NTOT * HCH * sizeof(ushort));
    ushort* Uh1  = (ushort*)alloc((size_t)NTOT * HCH * sizeof(ushort));
    ushort* AGGh = (ushort*)alloc((size_t)NTOT * HCH * sizeof(ushort));
    uint4* Braw  = (uint4*)alloc((size_t)30 * 4096 * sizeof(uint4));   // 1.97 MB raw-W fragments
    (void)ws_size; (void)in_sizes; (void)n_in; (void)out_size;

    hipMemsetAsync(d_ws, 0, zero_bytes, stream);
    k_wall   <<<480, 256, 0, stream>>>(Wb, Braw);
    k_hist   <<<EDGES / 256, 256, 0, stream>>>(dst, deg);
    k_scan   <<<1, 1024, 0, stream>>>(deg, rowptr, cursor);
    k_scatter<<<EDGES / 256, 256, 0, stream>>>(src, dst, L, cursor, epk);
    k_cnt    <<<NGRAPH, 256, 0, stream>>>(mask, gcnt);
    k_conv1  <<<NTOT / 128, 256, 0, stream>>>(x, W1, b1, H0, Uh0, sums);

    ushort* Ucur = Uh0; ushort* Unext = Uh1;
    for (int i = 0; i < 15; ++i){
        for (int j = 0; j < 2; ++j){
            int k = 2 * i + j;
            const uint4* Bk  = Braw + (size_t)k * 4096;
            const float* bk  = bb + (size_t)k * HCH;
            const float* gk  = gb + (size_t)k * 256;
            const float* bek = betab + (size_t)k * 256;
            float* sk = sums + (size_t)k * BANKS * 512;
            float* sn = sums + (size_t)(k + 1) * BANKS * 512;
            bool nextg  = (k < 29) && ((((k + 1) / 2) & 1) == 1);
            float* gsn = nextg ? (gsum + (size_t)(k + 1) * NGRAPH * HCH) : nullptr;
            if ((i & 1) == 0){
                k_spmm<<<NTOT / 16, 256, 0, stream>>>(Ucur, rowptr, epk, AGGh, sk);
                if (j == 0)
                    k_gemm<0,0><<<NTOT / 32, 256, 0, stream>>>(Ucur, AGGh, Bk, gk, bek, bk,
                                                               sk, nullptr, gcnt,
                                                               nullptr, nullptr, Unext, sn, mask, gsn);
                else
                    k_gemm<0,1><<<NTOT / 32, 256, 0, stream>>>(Ucur, AGGh, Bk, gk, bek, bk,
                                                               sk, nullptr, gcnt,
                                                               H0, H0, Unext, sn, mask, gsn);
            } else {
                float* gs = gsum + (size_t)k * NGRAPH * HCH;
                if (j == 0)
                    k_gemm<1,0><<<NTOT / 32, 256, 0, stream>>>(Ucur, nullptr, Bk, gk, bek, bk,
                                                               sk, gs, gcnt,
                                                               nullptr, nullptr, Unext, sn, mask, gsn);
                else
                    k_gemm<1,1><<<NTOT / 32, 256, 0, stream>>>(Ucur, nullptr, Bk, gk, bek, bk,
                                                               sk, gs, gcnt,
                                                               H0, H0, Unext, sn, mask, gsn);
            }
            ushort* tmp = Ucur; Ucur = Unext; Unext = tmp;
        }
    }
    k_final<<<NTOT / 64, 256, 0, stream>>>(Ucur, sums + (size_t)30 * BANKS * 512, g2, beta2, W2, b2, x, (float*)d_out);
}

// Round 17
// 764.850 us; speedup vs baseline: 5.1441x; 1.0092x over previous
//
#include <hip/hip_runtime.h>
#include <hip/hip_bf16.h>
#include <math.h>

#define NTOT   32768
#define NPER   4096
#define NGRAPH 8
#define EDGES  262144
#define HCH    128
#define EPSBN  1e-5f
#define BANKS  16

typedef short bf16x8 __attribute__((ext_vector_type(8)));
typedef float f32x4  __attribute__((ext_vector_type(4)));

__device__ __forceinline__ float eluf(float x){ return x > 0.f ? x : expm1f(x); }
__device__ __forceinline__ ushort f2bf(float f){
    uint u = __float_as_uint(f);
    u += 0x7fffu + ((u >> 16) & 1u);          // round-to-nearest-even
    return (ushort)(u >> 16);
}
__device__ __forceinline__ float bf2f(ushort h){ return __uint_as_float(((uint)h) << 16); }
__device__ __forceinline__ float bfhi(uint p){ return __uint_as_float(p & 0xffff0000u); }
__device__ __forceinline__ float bflo(uint p){ return __uint_as_float(p << 16); }

// ---------------- merged setup: wall | cnt | conv1 | hist (independent, one dispatch) ----------------
__global__ __launch_bounds__(256) void k_setup(
        const float* __restrict__ Wb, uint4* __restrict__ Braw,
        const float* __restrict__ mask, float* __restrict__ gcnt,
        const float* __restrict__ x, const float* __restrict__ W1,
        const float* __restrict__ b1, float* __restrict__ H,
        ushort* __restrict__ Uh, float* __restrict__ sums0,
        const int* __restrict__ dst, int* __restrict__ deg)
{
    const int bid = blockIdx.x;
    const int t = threadIdx.x;
    if (bid < 480){
        // ---- wall: all 30 layers' raw W -> fragment-native bf16 ----
        int layer = bid >> 4;
        int it = ((bid & 15) << 8) | t;
        int nt = it >> 9;
        int rem = it & 511;
        int kc = rem >> 6, l = rem & 63;
        int col = nt * 16 + (l & 15);
        int k0  = kc * 32 + (l >> 4) * 8;
        const float* W = Wb + (size_t)layer * 256 * HCH;
        ushort hi[8];
        #pragma unroll
        for (int q = 0; q < 8; ++q) hi[q] = f2bf(W[(size_t)(k0 + q) * HCH + col]);
        uint4 vh;
        vh.x = hi[0] | ((uint)hi[1] << 16); vh.y = hi[2] | ((uint)hi[3] << 16);
        vh.z = hi[4] | ((uint)hi[5] << 16); vh.w = hi[6] | ((uint)hi[7] << 16);
        Braw[(size_t)layer * 4096 + (size_t)(nt * 8 + kc) * 64 + l] = vh;
    } else if (bid < 488){
        // ---- cnt: per-graph mask count ----
        __shared__ float redc[4];
        int g = bid - 480;
        float s = 0.f;
        for (int i = t; i < NPER; i += 256) s += mask[g * NPER + i];
        #pragma unroll
        for (int off = 32; off > 0; off >>= 1) s += __shfl_down(s, off);
        if ((t & 63) == 0) redc[t >> 6] = s;
        __syncthreads();
        if (t == 0) gcnt[g] = redc[0] + redc[1] + redc[2] + redc[3];
    } else if (bid < 744){
        // ---- conv1: H = x@W1+b1 ; Uh = bf16(elu(H)) ; banked stats ----
        __shared__ float red[2][2][128];
        int ch = t & 127, pr = t >> 7;
        float w0 = W1[ch], w1 = W1[128 + ch], w2 = W1[256 + ch], bv = b1[ch];
        int base = (bid - 488) * 128;
        float ls = 0.f, lss = 0.f;
        for (int it = 0; it < 64; ++it){
            int row = base + 2 * it + pr;
            const float* xr = x + (size_t)row * 3;
            float h = fmaf(xr[2], w2, fmaf(xr[1], w1, fmaf(xr[0], w0, bv)));
            H[(size_t)row * HCH + ch] = h;
            float u = eluf(h);
            Uh[(size_t)row * HCH + ch] = f2bf(u);
            ls += u; lss += u * u;
        }
        red[0][pr][ch] = ls; red[1][pr][ch] = lss;
        __syncthreads();
        if (t < 128){
            float* sb_ = sums0 + (size_t)(bid & (BANKS - 1)) * 512;
            atomicAdd(&sb_[t],       red[0][0][t] + red[0][1][t]);
            atomicAdd(&sb_[256 + t], red[1][0][t] + red[1][1][t]);
        }
    } else {
        // ---- hist ----
        int e = (bid - 744) * 256 + t;
        atomicAdd(&deg[dst[e]], 1);
    }
}

__global__ __launch_bounds__(1024) void k_scan(const int* __restrict__ deg, int* __restrict__ rowptr,
                                               int* __restrict__ cursor){
    __shared__ int part[1024];
    int t = threadIdx.x;
    const int chunk = NTOT / 1024;
    int base = t * chunk;
    int s = 0;
    for (int j = 0; j < chunk; ++j) s += deg[base + j];
    part[t] = s; __syncthreads();
    for (int off = 1; off < 1024; off <<= 1){
        int v = (t >= off) ? part[t - off] : 0;
        __syncthreads();
        part[t] += v;
        __syncthreads();
    }
    int run = part[t] - s;
    for (int j = 0; j < chunk; ++j){
        rowptr[base + j] = run; cursor[base + j] = run;
        run += deg[base + j];
    }
    if (t == 1023) rowptr[NTOT] = run;
}

__global__ __launch_bounds__(256) void k_scatter(const int* __restrict__ src, const int* __restrict__ dst,
                                                 const float* __restrict__ L, int* __restrict__ cursor,
                                                 int2* __restrict__ epk){
    int e = blockIdx.x * 256 + threadIdx.x;
    int d = dst[e];
    int pos = atomicAdd(&cursor[d], 1);
    int2 pv; pv.x = src[e]; pv.y = __float_as_int(L[e]);
    epk[pos] = pv;
}

// ---------------- SpMM: 1 node / 16-lane group, 2048 blocks, batched-8 gather ----------------
__global__ __launch_bounds__(256) void k_spmm(const ushort* __restrict__ Uh, const int* __restrict__ rowptr,
                                              const int2* __restrict__ epk,
                                              ushort* __restrict__ AGGh, float* __restrict__ sums_k){
    __shared__ float red[2][16][128];
    const int t = threadIdx.x;
    const int rg = t >> 4, c8 = (t & 15) << 3;
    const int bid = blockIdx.x;
    const int sb = ((bid & 7) << 8) | (bid >> 3);   // graph -> XCD; 256 blocks per graph
    const int node = sb * 16 + rg;
    const int e0 = rowptr[node], e1 = rowptr[node + 1];

    auto acc8 = [](float* a, uint4 p, float wv){
        a[0] = fmaf(bflo(p.x), wv, a[0]); a[1] = fmaf(bfhi(p.x), wv, a[1]);
        a[2] = fmaf(bflo(p.y), wv, a[2]); a[3] = fmaf(bfhi(p.y), wv, a[3]);
        a[4] = fmaf(bflo(p.z), wv, a[4]); a[5] = fmaf(bfhi(p.z), wv, a[5]);
        a[6] = fmaf(bflo(p.w), wv, a[6]); a[7] = fmaf(bfhi(p.w), wv, a[7]);
    };

    float a[8] = {0,0,0,0,0,0,0,0};
    int e = e0;
    for (; e + 8 <= e1; e += 8){
        int2 PV[8];
        #pragma unroll
        for (int q = 0; q < 8; ++q) PV[q] = epk[e + q];
        uint4 P[8];
        #pragma unroll
        for (int q = 0; q < 8; ++q)
            P[q] = *(const uint4*)(Uh + (size_t)PV[q].x * HCH + c8);
        #pragma unroll
        for (int q = 0; q < 8; ++q) acc8(a, P[q], __int_as_float(PV[q].y));
    }
    for (; e + 2 <= e1; e += 2){
        int2 pv0 = epk[e], pv1 = epk[e + 1];
        uint4 p0 = *(const uint4*)(Uh + (size_t)pv0.x * HCH + c8);
        uint4 p1 = *(const uint4*)(Uh + (size_t)pv1.x * HCH + c8);
        acc8(a, p0, __int_as_float(pv0.y));
        acc8(a, p1, __int_as_float(pv1.y));
    }
    if (e < e1){
        int2 pv = epk[e];
        uint4 p = *(const uint4*)(Uh + (size_t)pv.x * HCH + c8);
        acc8(a, p, __int_as_float(pv.y));
    }
    uint4 o;
    o.x = (uint)f2bf(a[0]) | ((uint)f2bf(a[1]) << 16);
    o.y = (uint)f2bf(a[2]) | ((uint)f2bf(a[3]) << 16);
    o.z = (uint)f2bf(a[4]) | ((uint)f2bf(a[5]) << 16);
    o.w = (uint)f2bf(a[6]) | ((uint)f2bf(a[7]) << 16);
    *(uint4*)(AGGh + (size_t)node * HCH + c8) = o;

    #pragma unroll
    for (int j = 0; j < 8; ++j){
        red[0][rg][c8 + j] = a[j];
        red[1][rg][c8 + j] = a[j] * a[j];
    }
    __syncthreads();
    if (t < 128){
        float s = 0.f, q = 0.f;
        #pragma unroll
        for (int g = 0; g < 16; ++g){ s += red[0][g][t]; q += red[1][g][t]; }
        float* sb_ = sums_k + (size_t)(bid & (BANKS - 1)) * 512;
        atomicAdd(&sb_[128 + t], s);
        atomicAdd(&sb_[384 + t], q);
    }
}

// ---------------- MFMA GEMM (bf16 activations): BN folded into A at staging ----------------
template<int MODE, int RES>
__global__ __launch_bounds__(256) void k_gemm(
        const ushort* __restrict__ Uh, const ushort* __restrict__ AGGh,
        const uint4* __restrict__ Braw,
        const float* __restrict__ gamma, const float* __restrict__ beta,
        const float* __restrict__ bias,
        const float* __restrict__ sums_k, const float* __restrict__ gsum_k,
        const float* __restrict__ gcnt,
        const float* __restrict__ Hres, float* __restrict__ Hout,
        ushort* __restrict__ Uhout,
        float* __restrict__ sums_n, const float* __restrict__ mask,
        float* __restrict__ gsum_next)
{
    __shared__ ushort a_sm[4][2][512];        // per-wave 2x1KB dbuf (16 rows x 32 ch bf16)
    __shared__ float s_s[256], s_sh[256];
    __shared__ uint s_avgpk[64];              // MODE1 broadcast agg row, packed bf16 pairs
    __shared__ float red[2][2][128];
    __shared__ float gred[2][128];
    const int t = threadIdx.x;
    const int w = t >> 6, lane = t & 63;
    const int rlo = lane & 15, kg = lane >> 4;
    const int bid = blockIdx.x;
    const int sb  = ((bid & 7) << 7) | (bid >> 3);   // graph -> XCD
    const int row0 = sb * 32;
    const int wr0 = row0 + (w & 1) * 16;
    const int colbase = (w >> 1) * 64;
    const int ntb = (w >> 1) * 4;

    // ---- prologue: per-block BN affine ----
    {
        float m, ex2;
        if (MODE == 1 && t >= 128){
            float S1 = 0.f, S2 = 0.f;
            #pragma unroll
            for (int g = 0; g < NGRAPH; ++g){
                float a = gsum_k[g * 128 + (t - 128)] / gcnt[g];
                S1 += a; S2 += a * a;
            }
            m = S1 * (1.f / NGRAPH); ex2 = S2 * (1.f / NGRAPH);
        } else {
            float S = 0.f, Q = 0.f;
            #pragma unroll
            for (int b = 0; b < BANKS; ++b){
                S += sums_k[(size_t)b * 512 + t];
                Q += sums_k[(size_t)b * 512 + 256 + t];
            }
            m = S * (1.f / NTOT); ex2 = Q * (1.f / NTOT);
        }
        float var = ex2 - m * m;
        float sc = gamma[t] * rsqrtf(var + EPSBN);
        s_s[t] = sc; s_sh[t] = beta[t] - m * sc;
    }
    __syncthreads();
    if (MODE == 1){
        if (t < 64){
            int g0 = row0 >> 12;
            float a0 = gsum_k[g0 * 128 + 2 * t]     / gcnt[g0];
            float a1 = gsum_k[g0 * 128 + 2 * t + 1] / gcnt[g0];
            float z0 = fmaf(a0, s_s[128 + 2 * t],     s_sh[128 + 2 * t]);
            float z1 = fmaf(a1, s_s[128 + 2 * t + 1], s_sh[128 + 2 * t + 1]);
            s_avgpk[t] = (uint)f2bf(z0) | ((uint)f2bf(z1) << 16);
        }
        __syncthreads();
    }

    // stage 16 rows x 32 ch of normalized bf16; swizzle slot = sl ^ ((row>>1)&3)
    auto stage = [&](int kc, ushort* dst){
        int row = lane >> 2, sl = lane & 3;
        int ch = kc * 32 + sl * 8;
        const ushort* sp = (ch < 128)
            ? (Uh   + (size_t)(wr0 + row) * HCH + ch)
            : (AGGh + (size_t)(wr0 + row) * HCH + (ch - 128));
        uint4 v = *(const uint4*)sp;
        uint in[4] = {v.x, v.y, v.z, v.w};
        uint o[4];
        #pragma unroll
        for (int j = 0; j < 4; ++j){
            int c = ch + 2 * j;
            float z0 = fmaf(bflo(in[j]), s_s[c],     s_sh[c]);
            float z1 = fmaf(bfhi(in[j]), s_s[c + 1], s_sh[c + 1]);
            o[j] = (uint)f2bf(z0) | ((uint)f2bf(z1) << 16);
        }
        int slot = sl ^ ((row >> 1) & 3);
        uint4 wv = {o[0], o[1], o[2], o[3]};
        *(uint4*)&dst[row * 32 + slot * 8] = wv;
    };

    f32x4 acc[4];
    #pragma unroll
    for (int n = 0; n < 4; ++n) acc[n] = (f32x4){0.f, 0.f, 0.f, 0.f};

    stage(0, &a_sm[w][0][0]);
    #pragma unroll
    for (int kc = 0; kc < 8; ++kc){
        ushort* cur = &a_sm[w][kc & 1][0];
        ushort* nxt = &a_sm[w][(kc & 1) ^ 1][0];
        union { uint u[4]; bf16x8 v; } ah;
        if (MODE == 1 && kc >= 4){
            int base = (kc - 4) * 16 + kg * 4;
            ah.u[0] = s_avgpk[base + 0]; ah.u[1] = s_avgpk[base + 1];
            ah.u[2] = s_avgpk[base + 2]; ah.u[3] = s_avgpk[base + 3];
        } else {
            int slot = kg ^ ((rlo >> 1) & 3);
            uint4 c0 = *(const uint4*)&cur[rlo * 32 + slot * 8];
            ah.u[0] = c0.x; ah.u[1] = c0.y; ah.u[2] = c0.z; ah.u[3] = c0.w;
        }
        if (kc + 1 < ((MODE == 1) ? 4 : 8)) stage(kc + 1, nxt);
        #pragma unroll
        for (int n = 0; n < 4; ++n){
            const int nt = ntb + n;
            union { uint4 q; bf16x8 v; } bh;
            bh.q = Braw[(size_t)(nt * 8 + kc) * 64 + lane];
            acc[n] = __builtin_amdgcn_mfma_f32_16x16x32_bf16(ah.v, bh.v, acc[n], 0, 0, 0);
        }
    }

    // epilogue: bias (+res) -> h ; u = elu(h) ; bf16 store ; shfl-reduced stats
    const int r0 = wr0 + kg * 4;
    float mk[4] = {0.f, 0.f, 0.f, 0.f};
    if (gsum_next){ mk[0] = mask[r0]; mk[1] = mask[r0+1]; mk[2] = mask[r0+2]; mk[3] = mask[r0+3]; }
    #pragma unroll
    for (int n = 0; n < 4; ++n){
        const int c = colbase + n * 16 + rlo;
        const float bc = bias[c];
        float s = 0.f, q = 0.f, g = 0.f;
        #pragma unroll
        for (int r = 0; r < 4; ++r){
            int row = r0 + r;
            float h = acc[n][r] + bc;
            if (RES){
                h += Hres[(size_t)row * HCH + c];
                Hout[(size_t)row * HCH + c] = h;
            }
            float u = eluf(h);
            Uhout[(size_t)row * HCH + c] = f2bf(u);
            s += u; q += u * u;
            if (gsum_next) g = fmaf(u, mk[r], g);
        }
        s += __shfl_xor(s, 16); s += __shfl_xor(s, 32);
        q += __shfl_xor(q, 16); q += __shfl_xor(q, 32);
        if (gsum_next){ g += __shfl_xor(g, 16); g += __shfl_xor(g, 32); }
        if (kg == 0){
            red[0][w & 1][c] = s;
            red[1][w & 1][c] = q;
            if (gsum_next) gred[w & 1][c] = g;
        }
    }
    __syncthreads();
    if (t < 128){
        float a = red[0][0][t] + red[0][1][t];
        float b = red[1][0][t] + red[1][1][t];
        float* sb_ = sums_n + (size_t)(bid & (BANKS - 1)) * 512;
        atomicAdd(&sb_[t], a);
        atomicAdd(&sb_[256 + t], b);
        if (gsum_next)
            atomicAdd(&gsum_next[(row0 >> 12) * 128 + t], gred[0][t] + gred[1][t]);
    }
}

// ---------------- final: BN(elu(h)) @ W2 + b2 + x[:, :1] (banked stats) ----------------
__global__ __launch_bounds__(256) void k_final(const ushort* __restrict__ Uh, const float* __restrict__ sums30,
                                               const float* __restrict__ g2, const float* __restrict__ beta2,
                                               const float* __restrict__ W2, const float* __restrict__ b2,
                                               const float* __restrict__ x, float* __restrict__ out){
    __shared__ float s_s[128], s_sh[128];
    __shared__ float wred[4];
    int t = threadIdx.x;
    if (t < 128){
        float S = 0.f, Q = 0.f;
        for (int b = 0; b < BANKS; ++b){
            S += sums30[(size_t)b * 512 + t];
            Q += sums30[(size_t)b * 512 + 256 + t];
        }
        float m   = S * (1.f / NTOT);
        float ex2 = Q * (1.f / NTOT);
        float var = ex2 - m * m;
        float sc = g2[t] * rsqrtf(var + EPSBN);
        s_s[t] = sc; s_sh[t] = beta2[t] - m * sc;
    }
    __syncthreads();
    int lane = t & 63, wid = t >> 6;
    int ch = t & 127, pr = t >> 7;
    float w2 = W2[ch];
    float b2v = b2[0];
    int base = blockIdx.x * 64;
    for (int it = 0; it < 32; ++it){
        int rowa = base + it * 2;
        int row  = rowa + pr;
        float u = bf2f(Uh[(size_t)row * HCH + ch]);
        float v = (u * s_s[ch] + s_sh[ch]) * w2;
        #pragma unroll
        for (int off = 32; off > 0; off >>= 1) v += __shfl_down(v, off);
        if (lane == 0) wred[wid] = v;
        __syncthreads();
        if (t == 0)   out[rowa]     = wred[0] + wred[1] + b2v + x[(size_t)rowa * 3];
        if (t == 128) out[rowa + 1] = wred[2] + wred[3] + b2v + x[(size_t)(rowa + 1) * 3];
        __syncthreads();
    }
}

// ---------------- host ----------------
extern "C" void kernel_launch(void* const* d_in, const int* in_sizes, int n_in,
                              void* d_out, int out_size, void* d_ws, size_t ws_size,
                              hipStream_t stream){
    const float* x    = (const float*)d_in[0];
    const float* L    = (const float*)d_in[1];
    const float* mask = (const float*)d_in[2];
    const float* W1   = (const float*)d_in[3];
    const float* b1   = (const float*)d_in[4];
    const float* Wb   = (const float*)d_in[5];
    const float* bb   = (const float*)d_in[6];
    const float* gb   = (const float*)d_in[7];
    const float* betab= (const float*)d_in[8];
    const float* g2   = (const float*)d_in[9];
    const float* beta2= (const float*)d_in[10];
    const float* W2   = (const float*)d_in[11];
    const float* b2   = (const float*)d_in[12];
    const int*   src  = (const int*)d_in[13];
    const int*   dst  = (const int*)d_in[14];

    char* base = (char*)d_ws;
    size_t off = 0;
    auto alloc = [&](size_t bytes)->char*{
        char* r = base + off;
        off = (off + bytes + 255) & ~(size_t)255;
        return r;
    };
    float* sums  = (float*)alloc((size_t)31 * BANKS * 512 * sizeof(float));  // banked BN stats
    float* gsum  = (float*)alloc(30 * NGRAPH * HCH * sizeof(float));
    int*   deg   = (int*)  alloc(NTOT * sizeof(int));
    size_t zero_bytes = off;                                       // zeroed once per launch
    float* gcnt  = (float*)alloc(NGRAPH * sizeof(float));
    int*   cursor= (int*)  alloc(NTOT * sizeof(int));
    int*   rowptr= (int*)  alloc((NTOT + 1) * sizeof(int));
    int2*  epk   = (int2*) alloc(EDGES * sizeof(int2));
    float* H0    = (float*)alloc((size_t)NTOT * HCH * sizeof(float));
    ushort* Uh0  = (ushort*)alloc((size_t)NTOT * HCH * sizeof(ushort));
    ushort* Uh1  = (ushort*)alloc((size_t)NTOT * HCH * sizeof(ushort));
    ushort* AGGh = (ushort*)alloc((size_t)NTOT * HCH * sizeof(ushort));
    uint4* Braw  = (uint4*)alloc((size_t)30 * 4096 * sizeof(uint4));   // 1.97 MB raw-W fragments
    (void)ws_size; (void)in_sizes; (void)n_in; (void)out_size;

    hipMemsetAsync(d_ws, 0, zero_bytes, stream);
    k_setup  <<<1768, 256, 0, stream>>>(Wb, Braw, mask, gcnt, x, W1, b1, H0, Uh0, sums, dst, deg);
    k_scan   <<<1, 1024, 0, stream>>>(deg, rowptr, cursor);
    k_scatter<<<EDGES / 256, 256, 0, stream>>>(src, dst, L, cursor, epk);

    ushort* Ucur = Uh0; ushort* Unext = Uh1;
    for (int i = 0; i < 15; ++i){
        for (int j = 0; j < 2; ++j){
            int k = 2 * i + j;
            const uint4* Bk  = Braw + (size_t)k * 4096;
            const float* bk  = bb + (size_t)k * HCH;
            const float* gk  = gb + (size_t)k * 256;
            const float* bek = betab + (size_t)k * 256;
            float* sk = sums + (size_t)k * BANKS * 512;
            float* sn = sums + (size_t)(k + 1) * BANKS * 512;
            bool nextg  = (k < 29) && ((((k + 1) / 2) & 1) == 1);
            float* gsn = nextg ? (gsum + (size_t)(k + 1) * NGRAPH * HCH) : nullptr;
            if ((i & 1) == 0){
                k_spmm<<<NTOT / 16, 256, 0, stream>>>(Ucur, rowptr, epk, AGGh, sk);
                if (j == 0)
                    k_gemm<0,0><<<NTOT / 32, 256, 0, stream>>>(Ucur, AGGh, Bk, gk, bek, bk,
                                                               sk, nullptr, gcnt,
                                                               nullptr, nullptr, Unext, sn, mask, gsn);
                else
                    k_gemm<0,1><<<NTOT / 32, 256, 0, stream>>>(Ucur, AGGh, Bk, gk, bek, bk,
                                                               sk, nullptr, gcnt,
                                                               H0, H0, Unext, sn, mask, gsn);
            } else {
                float* gs = gsum + (size_t)k * NGRAPH * HCH;
                if (j == 0)
                    k_gemm<1,0><<<NTOT / 32, 256, 0, stream>>>(Ucur, nullptr, Bk, gk, bek, bk,
                                                               sk, gs, gcnt,
                                                               nullptr, nullptr, Unext, sn, mask, gsn);
                else
                    k_gemm<1,1><<<NTOT / 32, 256, 0, stream>>>(Ucur, nullptr, Bk, gk, bek, bk,
                                                               sk, gs, gcnt,
                                                               H0, H0, Unext, sn, mask, gsn);
            }
            ushort* tmp = Ucur; Ucur = Unext; Unext = tmp;
        }
    }
    k_final<<<NTOT / 64, 256, 0, stream>>>(Ucur, sums + (size_t)30 * BANKS * 512, g2, beta2, W2, b2, x, (float*)d_out);
}

// Round 18
// 755.373 us; speedup vs baseline: 5.2086x; 1.0125x over previous
//
#include <hip/hip_runtime.h>
#include <hip/hip_bf16.h>
#include <math.h>

#define NTOT   32768
#define NPER   4096
#define NGRAPH 8
#define EDGES  262144
#define HCH    128
#define EPSBN  1e-5f
#define BANKS  16

typedef short bf16x8 __attribute__((ext_vector_type(8)));
typedef float f32x4  __attribute__((ext_vector_type(4)));

__device__ __forceinline__ float eluf(float x){ return x > 0.f ? x : expm1f(x); }
__device__ __forceinline__ ushort f2bf(float f){
    uint u = __float_as_uint(f);
    u += 0x7fffu + ((u >> 16) & 1u);          // round-to-nearest-even
    return (ushort)(u >> 16);
}
__device__ __forceinline__ float bf2f(ushort h){ return __uint_as_float(((uint)h) << 16); }
__device__ __forceinline__ float bfhi(uint p){ return __uint_as_float(p & 0xffff0000u); }
__device__ __forceinline__ float bflo(uint p){ return __uint_as_float(p << 16); }

// ---------------- merged setup: wall | cnt | conv1 | hist (independent, one dispatch) ----------------
__global__ __launch_bounds__(256) void k_setup(
        const float* __restrict__ Wb, uint4* __restrict__ Braw,
        const float* __restrict__ mask, float* __restrict__ gcnt,
        const float* __restrict__ x, const float* __restrict__ W1,
        const float* __restrict__ b1, float* __restrict__ H,
        ushort* __restrict__ Uh, float* __restrict__ sums0,
        const int* __restrict__ dst, int* __restrict__ deg)
{
    const int bid = blockIdx.x;
    const int t = threadIdx.x;
    if (bid < 480){
        // ---- wall: all 30 layers' raw W -> fragment-native bf16 ----
        int layer = bid >> 4;
        int it = ((bid & 15) << 8) | t;
        int nt = it >> 9;
        int rem = it & 511;
        int kc = rem >> 6, l = rem & 63;
        int col = nt * 16 + (l & 15);
        int k0  = kc * 32 + (l >> 4) * 8;
        const float* W = Wb + (size_t)layer * 256 * HCH;
        ushort hi[8];
        #pragma unroll
        for (int q = 0; q < 8; ++q) hi[q] = f2bf(W[(size_t)(k0 + q) * HCH + col]);
        uint4 vh;
        vh.x = hi[0] | ((uint)hi[1] << 16); vh.y = hi[2] | ((uint)hi[3] << 16);
        vh.z = hi[4] | ((uint)hi[5] << 16); vh.w = hi[6] | ((uint)hi[7] << 16);
        Braw[(size_t)layer * 4096 + (size_t)(nt * 8 + kc) * 64 + l] = vh;
    } else if (bid < 488){
        // ---- cnt: per-graph mask count ----
        __shared__ float redc[4];
        int g = bid - 480;
        float s = 0.f;
        for (int i = t; i < NPER; i += 256) s += mask[g * NPER + i];
        #pragma unroll
        for (int off = 32; off > 0; off >>= 1) s += __shfl_down(s, off);
        if ((t & 63) == 0) redc[t >> 6] = s;
        __syncthreads();
        if (t == 0) gcnt[g] = redc[0] + redc[1] + redc[2] + redc[3];
    } else if (bid < 744){
        // ---- conv1: H = x@W1+b1 ; Uh = bf16(elu(H)) ; banked stats ----
        __shared__ float red[2][2][128];
        int ch = t & 127, pr = t >> 7;
        float w0 = W1[ch], w1 = W1[128 + ch], w2 = W1[256 + ch], bv = b1[ch];
        int base = (bid - 488) * 128;
        float ls = 0.f, lss = 0.f;
        for (int it = 0; it < 64; ++it){
            int row = base + 2 * it + pr;
            const float* xr = x + (size_t)row * 3;
            float h = fmaf(xr[2], w2, fmaf(xr[1], w1, fmaf(xr[0], w0, bv)));
            H[(size_t)row * HCH + ch] = h;
            float u = eluf(h);
            Uh[(size_t)row * HCH + ch] = f2bf(u);
            ls += u; lss += u * u;
        }
        red[0][pr][ch] = ls; red[1][pr][ch] = lss;
        __syncthreads();
        if (t < 128){
            float* sb_ = sums0 + (size_t)(bid & (BANKS - 1)) * 512;
            atomicAdd(&sb_[t],       red[0][0][t] + red[0][1][t]);
            atomicAdd(&sb_[256 + t], red[1][0][t] + red[1][1][t]);
        }
    } else {
        // ---- hist ----
        int e = (bid - 744) * 256 + t;
        atomicAdd(&deg[dst[e]], 1);
    }
}

__global__ __launch_bounds__(1024) void k_scan(const int* __restrict__ deg, int* __restrict__ rowptr,
                                               int* __restrict__ cursor){
    __shared__ int part[1024];
    int t = threadIdx.x;
    const int chunk = NTOT / 1024;
    int base = t * chunk;
    int s = 0;
    for (int j = 0; j < chunk; ++j) s += deg[base + j];
    part[t] = s; __syncthreads();
    for (int off = 1; off < 1024; off <<= 1){
        int v = (t >= off) ? part[t - off] : 0;
        __syncthreads();
        part[t] += v;
        __syncthreads();
    }
    int run = part[t] - s;
    for (int j = 0; j < chunk; ++j){
        rowptr[base + j] = run; cursor[base + j] = run;
        run += deg[base + j];
    }
    if (t == 1023) rowptr[NTOT] = run;
}

__global__ __launch_bounds__(256) void k_scatter(const int* __restrict__ src, const int* __restrict__ dst,
                                                 const float* __restrict__ L, int* __restrict__ cursor,
                                                 int2* __restrict__ epk){
    int e = blockIdx.x * 256 + threadIdx.x;
    int d = dst[e];
    int pos = atomicAdd(&cursor[d], 1);
    int2 pv; pv.x = src[e]; pv.y = __float_as_int(L[e]);
    epk[pos] = pv;
}

// ---------------- SpMM: 1 node / 16-lane group, batched-8 gather + masked-8 tail ----------------
__global__ __launch_bounds__(256) void k_spmm(const ushort* __restrict__ Uh, const int* __restrict__ rowptr,
                                              const int2* __restrict__ epk,
                                              ushort* __restrict__ AGGh, float* __restrict__ sums_k){
    __shared__ float red[2][16][128];
    const int t = threadIdx.x;
    const int rg = t >> 4, c8 = (t & 15) << 3;
    const int bid = blockIdx.x;
    const int sb = ((bid & 7) << 8) | (bid >> 3);   // graph -> XCD; 256 blocks per graph
    const int node = sb * 16 + rg;
    const int e0 = rowptr[node], e1 = rowptr[node + 1];

    auto acc8 = [](float* a, uint4 p, float wv){
        a[0] = fmaf(bflo(p.x), wv, a[0]); a[1] = fmaf(bfhi(p.x), wv, a[1]);
        a[2] = fmaf(bflo(p.y), wv, a[2]); a[3] = fmaf(bfhi(p.y), wv, a[3]);
        a[4] = fmaf(bflo(p.z), wv, a[4]); a[5] = fmaf(bfhi(p.z), wv, a[5]);
        a[6] = fmaf(bflo(p.w), wv, a[6]); a[7] = fmaf(bfhi(p.w), wv, a[7]);
    };

    float a[8] = {0,0,0,0,0,0,0,0};
    int e = e0;
    for (; e + 8 <= e1; e += 8){
        int2 PV[8];
        #pragma unroll
        for (int q = 0; q < 8; ++q) PV[q] = epk[e + q];
        uint4 P[8];
        #pragma unroll
        for (int q = 0; q < 8; ++q)
            P[q] = *(const uint4*)(Uh + (size_t)PV[q].x * HCH + c8);
        #pragma unroll
        for (int q = 0; q < 8; ++q) acc8(a, P[q], __int_as_float(PV[q].y));
    }
    if (e < e1){
        // masked batch-8 tail: one round-trip for any remainder; w=0 lanes are exact no-ops
        const int last = e1 - 1;
        int2 PV[8];
        #pragma unroll
        for (int q = 0; q < 8; ++q){
            int ee = (e + q < e1) ? (e + q) : last;
            PV[q] = epk[ee];
        }
        uint4 P[8];
        #pragma unroll
        for (int q = 0; q < 8; ++q)
            P[q] = *(const uint4*)(Uh + (size_t)PV[q].x * HCH + c8);
        #pragma unroll
        for (int q = 0; q < 8; ++q){
            float wv = (e + q < e1) ? __int_as_float(PV[q].y) : 0.f;
            acc8(a, P[q], wv);
        }
    }
    uint4 o;
    o.x = (uint)f2bf(a[0]) | ((uint)f2bf(a[1]) << 16);
    o.y = (uint)f2bf(a[2]) | ((uint)f2bf(a[3]) << 16);
    o.z = (uint)f2bf(a[4]) | ((uint)f2bf(a[5]) << 16);
    o.w = (uint)f2bf(a[6]) | ((uint)f2bf(a[7]) << 16);
    *(uint4*)(AGGh + (size_t)node * HCH + c8) = o;

    #pragma unroll
    for (int j = 0; j < 8; ++j){
        red[0][rg][c8 + j] = a[j];
        red[1][rg][c8 + j] = a[j] * a[j];
    }
    __syncthreads();
    if (t < 128){
        float s = 0.f, q = 0.f;
        #pragma unroll
        for (int g = 0; g < 16; ++g){ s += red[0][g][t]; q += red[1][g][t]; }
        float* sb_ = sums_k + (size_t)(bid & (BANKS - 1)) * 512;
        atomicAdd(&sb_[128 + t], s);
        atomicAdd(&sb_[384 + t], q);
    }
}

// ---------------- MFMA GEMM (bf16 activations): BN folded into A at staging ----------------
template<int MODE, int RES>
__global__ __launch_bounds__(256) void k_gemm(
        const ushort* __restrict__ Uh, const ushort* __restrict__ AGGh,
        const uint4* __restrict__ Braw,
        const float* __restrict__ gamma, const float* __restrict__ beta,
        const float* __restrict__ bias,
        const float* __restrict__ sums_k, const float* __restrict__ gsum_k,
        const float* __restrict__ gcnt,
        const float* __restrict__ Hres, float* __restrict__ Hout,
        ushort* __restrict__ Uhout,
        float* __restrict__ sums_n, const float* __restrict__ mask,
        float* __restrict__ gsum_next)
{
    __shared__ ushort a_sm[4][2][512];        // per-wave 2x1KB dbuf (16 rows x 32 ch bf16)
    __shared__ float s_s[256], s_sh[256];
    __shared__ uint s_avgpk[64];              // MODE1 broadcast agg row, packed bf16 pairs
    __shared__ float red[2][2][128];
    __shared__ float gred[2][128];
    const int t = threadIdx.x;
    const int w = t >> 6, lane = t & 63;
    const int rlo = lane & 15, kg = lane >> 4;
    const int bid = blockIdx.x;
    const int sb  = ((bid & 7) << 7) | (bid >> 3);   // graph -> XCD
    const int row0 = sb * 32;
    const int wr0 = row0 + (w & 1) * 16;
    const int colbase = (w >> 1) * 64;
    const int ntb = (w >> 1) * 4;

    // ---- prologue: per-block BN affine ----
    {
        float m, ex2;
        if (MODE == 1 && t >= 128){
            float S1 = 0.f, S2 = 0.f;
            #pragma unroll
            for (int g = 0; g < NGRAPH; ++g){
                float a = gsum_k[g * 128 + (t - 128)] / gcnt[g];
                S1 += a; S2 += a * a;
            }
            m = S1 * (1.f / NGRAPH); ex2 = S2 * (1.f / NGRAPH);
        } else {
            float S = 0.f, Q = 0.f;
            #pragma unroll
            for (int b = 0; b < BANKS; ++b){
                S += sums_k[(size_t)b * 512 + t];
                Q += sums_k[(size_t)b * 512 + 256 + t];
            }
            m = S * (1.f / NTOT); ex2 = Q * (1.f / NTOT);
        }
        float var = ex2 - m * m;
        float sc = gamma[t] * rsqrtf(var + EPSBN);
        s_s[t] = sc; s_sh[t] = beta[t] - m * sc;
    }
    __syncthreads();
    if (MODE == 1){
        if (t < 64){
            int g0 = row0 >> 12;
            float a0 = gsum_k[g0 * 128 + 2 * t]     / gcnt[g0];
            float a1 = gsum_k[g0 * 128 + 2 * t + 1] / gcnt[g0];
            float z0 = fmaf(a0, s_s[128 + 2 * t],     s_sh[128 + 2 * t]);
            float z1 = fmaf(a1, s_s[128 + 2 * t + 1], s_sh[128 + 2 * t + 1]);
            s_avgpk[t] = (uint)f2bf(z0) | ((uint)f2bf(z1) << 16);
        }
        __syncthreads();
    }

    // stage 16 rows x 32 ch of normalized bf16; swizzle slot = sl ^ ((row>>1)&3)
    auto stage = [&](int kc, ushort* dst){
        int row = lane >> 2, sl = lane & 3;
        int ch = kc * 32 + sl * 8;
        const ushort* sp = (ch < 128)
            ? (Uh   + (size_t)(wr0 + row) * HCH + ch)
            : (AGGh + (size_t)(wr0 + row) * HCH + (ch - 128));
        uint4 v = *(const uint4*)sp;
        uint in[4] = {v.x, v.y, v.z, v.w};
        uint o[4];
        #pragma unroll
        for (int j = 0; j < 4; ++j){
            int c = ch + 2 * j;
            float z0 = fmaf(bflo(in[j]), s_s[c],     s_sh[c]);
            float z1 = fmaf(bfhi(in[j]), s_s[c + 1], s_sh[c + 1]);
            o[j] = (uint)f2bf(z0) | ((uint)f2bf(z1) << 16);
        }
        int slot = sl ^ ((row >> 1) & 3);
        uint4 wv = {o[0], o[1], o[2], o[3]};
        *(uint4*)&dst[row * 32 + slot * 8] = wv;
    };

    f32x4 acc[4];
    #pragma unroll
    for (int n = 0; n < 4; ++n) acc[n] = (f32x4){0.f, 0.f, 0.f, 0.f};

    stage(0, &a_sm[w][0][0]);
    #pragma unroll
    for (int kc = 0; kc < 8; ++kc){
        ushort* cur = &a_sm[w][kc & 1][0];
        ushort* nxt = &a_sm[w][(kc & 1) ^ 1][0];
        union { uint u[4]; bf16x8 v; } ah;
        if (MODE == 1 && kc >= 4){
            int base = (kc - 4) * 16 + kg * 4;
            ah.u[0] = s_avgpk[base + 0]; ah.u[1] = s_avgpk[base + 1];
            ah.u[2] = s_avgpk[base + 2]; ah.u[3] = s_avgpk[base + 3];
        } else {
            int slot = kg ^ ((rlo >> 1) & 3);
            uint4 c0 = *(const uint4*)&cur[rlo * 32 + slot * 8];
            ah.u[0] = c0.x; ah.u[1] = c0.y; ah.u[2] = c0.z; ah.u[3] = c0.w;
        }
        if (kc + 1 < ((MODE == 1) ? 4 : 8)) stage(kc + 1, nxt);
        #pragma unroll
        for (int n = 0; n < 4; ++n){
            const int nt = ntb + n;
            union { uint4 q; bf16x8 v; } bh;
            bh.q = Braw[(size_t)(nt * 8 + kc) * 64 + lane];
            acc[n] = __builtin_amdgcn_mfma_f32_16x16x32_bf16(ah.v, bh.v, acc[n], 0, 0, 0);
        }
    }

    // epilogue: bias (+res) -> h ; u = elu(h) ; bf16 store ; shfl-reduced stats
    const int r0 = wr0 + kg * 4;
    float mk[4] = {0.f, 0.f, 0.f, 0.f};
    if (gsum_next){ mk[0] = mask[r0]; mk[1] = mask[r0+1]; mk[2] = mask[r0+2]; mk[3] = mask[r0+3]; }
    #pragma unroll
    for (int n = 0; n < 4; ++n){
        const int c = colbase + n * 16 + rlo;
        const float bc = bias[c];
        float s = 0.f, q = 0.f, g = 0.f;
        #pragma unroll
        for (int r = 0; r < 4; ++r){
            int row = r0 + r;
            float h = acc[n][r] + bc;
            if (RES){
                h += Hres[(size_t)row * HCH + c];
                Hout[(size_t)row * HCH + c] = h;
            }
            float u = eluf(h);
            Uhout[(size_t)row * HCH + c] = f2bf(u);
            s += u; q += u * u;
            if (gsum_next) g = fmaf(u, mk[r], g);
        }
        s += __shfl_xor(s, 16); s += __shfl_xor(s, 32);
        q += __shfl_xor(q, 16); q += __shfl_xor(q, 32);
        if (gsum_next){ g += __shfl_xor(g, 16); g += __shfl_xor(g, 32); }
        if (kg == 0){
            red[0][w & 1][c] = s;
            red[1][w & 1][c] = q;
            if (gsum_next) gred[w & 1][c] = g;
        }
    }
    __syncthreads();
    if (t < 128){
        float a = red[0][0][t] + red[0][1][t];
        float b = red[1][0][t] + red[1][1][t];
        float* sb_ = sums_n + (size_t)(bid & (BANKS - 1)) * 512;
        atomicAdd(&sb_[t], a);
        atomicAdd(&sb_[256 + t], b);
        if (gsum_next)
            atomicAdd(&gsum_next[(row0 >> 12) * 128 + t], gred[0][t] + gred[1][t]);
    }
}

// ---------------- final: BN(elu(h)) @ W2 + b2 + x[:, :1] (banked stats) ----------------
__global__ __launch_bounds__(256) void k_final(const ushort* __restrict__ Uh, const float* __restrict__ sums30,
                                               const float* __restrict__ g2, const float* __restrict__ beta2,
                                               const float* __restrict__ W2, const float* __restrict__ b2,
                                               const float* __restrict__ x, float* __restrict__ out){
    __shared__ float s_s[128], s_sh[128];
    __shared__ float wred[4];
    int t = threadIdx.x;
    if (t < 128){
        float S = 0.f, Q = 0.f;
        for (int b = 0; b < BANKS; ++b){
            S += sums30[(size_t)b * 512 + t];
            Q += sums30[(size_t)b * 512 + 256 + t];
        }
        float m   = S * (1.f / NTOT);
        float ex2 = Q * (1.f / NTOT);
        float var = ex2 - m * m;
        float sc = g2[t] * rsqrtf(var + EPSBN);
        s_s[t] = sc; s_sh[t] = beta2[t] - m * sc;
    }
    __syncthreads();
    int lane = t & 63, wid = t >> 6;
    int ch = t & 127, pr = t >> 7;
    float w2 = W2[ch];
    float b2v = b2[0];
    int base = blockIdx.x * 64;
    for (int it = 0; it < 32; ++it){
        int rowa = base + it * 2;
        int row  = rowa + pr;
        float u = bf2f(Uh[(size_t)row * HCH + ch]);
        float v = (u * s_s[ch] + s_sh[ch]) * w2;
        #pragma unroll
        for (int off = 32; off > 0; off >>= 1) v += __shfl_down(v, off);
        if (lane == 0) wred[wid] = v;
        __syncthreads();
        if (t == 0)   out[rowa]     = wred[0] + wred[1] + b2v + x[(size_t)rowa * 3];
        if (t == 128) out[rowa + 1] = wred[2] + wred[3] + b2v + x[(size_t)(rowa + 1) * 3];
        __syncthreads();
    }
}

// ---------------- host ----------------
extern "C" void kernel_launch(void* const* d_in, const int* in_sizes, int n_in,
                              void* d_out, int out_size, void* d_ws, size_t ws_size,
                              hipStream_t stream){
    const float* x    = (const float*)d_in[0];
    const float* L    = (const float*)d_in[1];
    const float* mask = (const float*)d_in[2];
    const float* W1   = (const float*)d_in[3];
    const float* b1   = (const float*)d_in[4];
    const float* Wb   = (const float*)d_in[5];
    const float* bb   = (const float*)d_in[6];
    const float* gb   = (const float*)d_in[7];
    const float* betab= (const float*)d_in[8];
    const float* g2   = (const float*)d_in[9];
    const float* beta2= (const float*)d_in[10];
    const float* W2   = (const float*)d_in[11];
    const float* b2   = (const float*)d_in[12];
    const int*   src  = (const int*)d_in[13];
    const int*   dst  = (const int*)d_in[14];

    char* base = (char*)d_ws;
    size_t off = 0;
    auto alloc = [&](size_t bytes)->char*{
        char* r = base + off;
        off = (off + bytes + 255) & ~(size_t)255;
        return r;
    };
    float* sums  = (float*)alloc((size_t)31 * BANKS * 512 * sizeof(float));  // banked BN stats
    float* gsum  = (float*)alloc(30 * NGRAPH * HCH * sizeof(float));
    int*   deg   = (int*)  alloc(NTOT * sizeof(int));
    size_t zero_bytes = off;                                       // zeroed once per launch
    float* gcnt  = (float*)alloc(NGRAPH * sizeof(float));
    int*   cursor= (int*)  alloc(NTOT * sizeof(int));
    int*   rowptr= (int*)  alloc((NTOT + 1) * sizeof(int));
    int2*  epk   = (int2*) alloc(EDGES * sizeof(int2));
    float* H0    = (float*)alloc((size_t)NTOT * HCH * sizeof(float));
    ushort* Uh0  = (ushort*)alloc((size_t)NTOT * HCH * sizeof(ushort));
    ushort* Uh1  = (ushort*)alloc((size_t)NTOT * HCH * sizeof(ushort));
    ushort* AGGh = (ushort*)alloc((size_t)NTOT * HCH * sizeof(ushort));
    uint4* Braw  = (uint4*)alloc((size_t)30 * 4096 * sizeof(uint4));   // 1.97 MB raw-W fragments
    (void)ws_size; (void)in_sizes; (void)n_in; (void)out_size;

    hipMemsetAsync(d_ws, 0, zero_bytes, stream);
    k_setup  <<<1768, 256, 0, stream>>>(Wb, Braw, mask, gcnt, x, W1, b1, H0, Uh0, sums, dst, deg);
    k_scan   <<<1, 1024, 0, stream>>>(deg, rowptr, cursor);
    k_scatter<<<EDGES / 256, 256, 0, stream>>>(src, dst, L, cursor, epk);

    ushort* Ucur = Uh0; ushort* Unext = Uh1;
    for (int i = 0; i < 15; ++i){
        for (int j = 0; j < 2; ++j){
            int k = 2 * i + j;
            const uint4* Bk  = Braw + (size_t)k * 4096;
            const float* bk  = bb + (size_t)k * HCH;
            const float* gk  = gb + (size_t)k * 256;
            const float* bek = betab + (size_t)k * 256;
            float* sk = sums + (size_t)k * BANKS * 512;
            float* sn = sums + (size_t)(k + 1) * BANKS * 512;
            bool nextg  = (k < 29) && ((((k + 1) / 2) & 1) == 1);
            float* gsn = nextg ? (gsum + (size_t)(k + 1) * NGRAPH * HCH) : nullptr;
            if ((i & 1) == 0){
                k_spmm<<<NTOT / 16, 256, 0, stream>>>(Ucur, rowptr, epk, AGGh, sk);
                if (j == 0)
                    k_gemm<0,0><<<NTOT / 32, 256, 0, stream>>>(Ucur, AGGh, Bk, gk, bek, bk,
                                                               sk, nullptr, gcnt,
                                                               nullptr, nullptr, Unext, sn, mask, gsn);
                else
                    k_gemm<0,1><<<NTOT / 32, 256, 0, stream>>>(Ucur, AGGh, Bk, gk, bek, bk,
                                                               sk, nullptr, gcnt,
                                                               H0, H0, Unext, sn, mask, gsn);
            } else {
                float* gs = gsum + (size_t)k * NGRAPH * HCH;
                if (j == 0)
                    k_gemm<1,0><<<NTOT / 32, 256, 0, stream>>>(Ucur, nullptr, Bk, gk, bek, bk,
                                                               sk, gs, gcnt,
                                                               nullptr, nullptr, Unext, sn, mask, gsn);
                else
                    k_gemm<1,1><<<NTOT / 32, 256, 0, stream>>>(Ucur, nullptr, Bk, gk, bek, bk,
                                                               sk, gs, gcnt,
                                                               H0, H0, Unext, sn, mask, gsn);
            }
            ushort* tmp = Ucur; Ucur = Unext; Unext = tmp;
        }
    }
    k_final<<<NTOT / 64, 256, 0, stream>>>(Ucur, sums + (size_t)30 * BANKS * 512, g2, beta2, W2, b2, x, (float*)d_out);
}